// Round 9
// baseline (3546.875 us; speedup 1.0000x reference)
//
#include <hip/hip_runtime.h>

#define NB 32
#define NT 512
#define NI 128
#define NH 1024
#define NG 4096
#define NO 128

typedef _Float16 f16;
typedef _Float16 f16x8 __attribute__((ext_vector_type(8)));
typedef float f32x4 __attribute__((ext_vector_type(4)));
typedef int int4v __attribute__((ext_vector_type(4)));
typedef unsigned long long ull;

#define MFMA16(a, b, c) __builtin_amdgcn_mfma_f32_16x16x32_f16(a, b, c, 0, 0, 0)
#define SENTD 0x7F7F7F7Fu

__device__ __forceinline__ float sigm(float x) { return 1.f / (1.f + __expf(-x)); }
__device__ __forceinline__ float tanh_(float x) {
    float a = fabsf(x);
    float e = __expf(-2.f * a);
    float r = (1.f - e) / (1.f + e);
    return x < 0.f ? -r : r;
}
// valid when NO dword equals the 0x7F7F7F7F sentinel (f16 NaN pair; |h|<1
// so real packed h never encodes as it)
__device__ __forceinline__ bool ok16(int4v v) {
    return v.x != (int)SENTD && v.y != (int)SENTD && v.z != (int)SENTD && v.w != (int)SENTD;
}
__device__ __forceinline__ void astore64(void* p, ull v) {
    __hip_atomic_store((ull*)p, v, __ATOMIC_RELAXED, __HIP_MEMORY_SCOPE_AGENT);
}
__device__ __forceinline__ void astore32u(void* p, unsigned v) {
    __hip_atomic_store((unsigned*)p, v, __ATOMIC_RELAXED, __HIP_MEMORY_SCOPE_AGENT);
}
__device__ __forceinline__ f16x8 ld8f(const float* s) {
    float4 x0 = *(const float4*)s, x1 = *(const float4*)(s + 4);
    f16x8 v;
    v[0] = (f16)x0.x; v[1] = (f16)x0.y; v[2] = (f16)x0.z; v[3] = (f16)x0.w;
    v[4] = (f16)x1.x; v[5] = (f16)x1.y; v[6] = (f16)x1.z; v[7] = (f16)x1.w;
    return v;
}
// 16B load, L1+L2-bypass (L3-direct): retry/fallback path
#define LOAD_SC01(dst, addr) \
    asm volatile("global_load_dwordx4 %0, %1, off sc0 sc1" : "=v"(dst) : "v"(addr))
// 4B flag load, L1+L2-bypass (cannot plant stale lines)
#define LOAD_DW_SC01(dst, addr) \
    asm volatile("global_load_dword %0, %1, off sc0 sc1" : "=v"(dst) : "v"(addr))
#define WAITV0() do { asm volatile("s_waitcnt vmcnt(0)" ::: "memory"); \
                      __builtin_amdgcn_sched_barrier(0); } while (0)

__global__ void convf16(const float* __restrict__ src, f16* __restrict__ dst, int n) {
    int i = blockIdx.x * blockDim.x + threadIdx.x;
    if (i < n) dst[i] = (f16)src[i];
}

// ---------------------------------------------------------------------------
// Persistent pipeline (R8 structure + flag-gated L2-shared reads):
// 256 WGs x 256 thr, 1 WG/CU (forced by 84KB dyn LDS).
//  bid [0,128)   R1: layer-1 step, (16 batch, 16 units)/CU, K=1152 (state|h1).
//  bid [128,256) R2: layer-2 step + input proj, (16 batch, 16 units)/CU,
//                two K=1024 matmuls (h1[t]@Wih1 + h2[t-1]@Whh1).
// Weights in VGPRs. Producers publish packed 8B agent-atomic stores (L3),
// then per-CU ready flag (after vmcnt(0)+barrier => data committed first).
// Consumers poll the 64 producer flags with SC01 dword loads (no stale-line
// risk), then bulk-read h with PLAIN cacheable loads: lines are untouched
// before the flag trips (kernel-boundary acquire invalidates L2 across
// replays), so the first touch fills L2 from fresh L3 data and same-XCD
// CUs share it. Sentinel check + SC01 retry kept as unconditional fallback
// (any race degrades to R8's proven path). Deadlock-impossible.
// ---------------------------------------------------------------------------
extern "C" __global__ __launch_bounds__(256, 1) void persist(
    const float* __restrict__ Wih0f, const float* __restrict__ Whh0f, const float* __restrict__ b0,
    const float* __restrict__ Wih1f, const float* __restrict__ Whh1f, const float* __restrict__ b1,
    const f16* __restrict__ state16,
    f16* __restrict__ h1all,      // [NT][NB][NH], 0x7F-filled
    f16* __restrict__ h2all,      // [NT][NB][NH], 0x7F-filled
    unsigned* __restrict__ flags1,  // [NT][128], 0-filled
    unsigned* __restrict__ flags2)  // [NT][128], 0-filled
{
    extern __shared__ char smem[];
    float* gbuf = (float*)smem;   // [16][16*17] f32 partials, +17 pad
    const int bid = blockIdx.x;
    const int tid = threadIdx.x;
    const int w = tid >> 6;
    const int lane = tid & 63;
    const int llo = lane & 15;
    const int lhi = lane >> 4;
    const int rb = tid >> 2;        // elementwise: batch row (threads 0..63)
    const int uq = (tid & 3) * 4;   // elementwise: unit quad base

    if (bid < 128) {
        // ============================ R1 ============================
        const int bs = bid >> 6, us = bid & 63;
        const int bbase = bs * 16, ubase = us * 16;
        // weights: wave w owns ks = w*9+i (K=1152), 4 gate-column blocks
        f16x8 wr[36];
#pragma unroll
        for (int g = 0; g < 4; ++g)
#pragma unroll
            for (int i = 0; i < 9; ++i) {
                int kpos = (w * 9 + i) * 32 + lhi * 8;
                int col = g * NH + ubase + llo;
                const float* s = (kpos < 128) ? (Wih0f + (size_t)col * NI + kpos)
                                              : (Whh0f + (size_t)col * NH + (kpos - 128));
                wr[g * 9 + i] = ld8f(s);
            }
        float cc[4] = {0.f, 0.f, 0.f, 0.f};
        float Bi[4], Bff[4], Bg[4], Bo[4];
        if (tid < 64) {
#pragma unroll
            for (int u = 0; u < 4; ++u) {
                Bi[u]  = b0[0 * NH + ubase + uq + u];
                Bff[u] = b0[1 * NH + ubase + uq + u];
                Bg[u]  = b0[2 * NH + ubase + uq + u];
                Bo[u]  = b0[3 * NH + ubase + uq + u];
            }
        }

        for (int t = 0; t < NT; ++t) {
            const f16* hprev = h1all + (size_t)(t - 1) * NB * NH;
            const int row = bbase + llo;
            // ---- flag gate: wait for all 64 producers of h1[t-1] (this bs) ----
            if (t > 0) {
                if (w == 0) {
                    const unsigned* fp = flags1 + (size_t)(t - 1) * 128 + bs * 64 + lane;
                    int r = 0;
                    for (;;) {
                        unsigned v; LOAD_DW_SC01(v, fp); WAITV0();
                        if (__all(v != 0)) break;
                        if (++r > 8) __builtin_amdgcn_s_sleep(1);
                    }
                }
                __syncthreads();   // B1: flags confirmed for whole WG
            }
            // ---- bulk plain (cacheable, L2-shared) loads; sentinel safety net ----
            int4v vv[9];
#pragma unroll
            for (int i = 0; i < 9; ++i) {
                int kpos = (w * 9 + i) * 32 + lhi * 8;
                if (kpos < 128)
                    vv[i] = *(const int4v*)(state16 + ((size_t)row * NT + t) * NI + kpos);
                else if (t > 0)
                    vv[i] = *(const int4v*)(hprev + (size_t)row * NH + (kpos - 128));
                else
                    vv[i] = int4v{};
            }
            if (t > 0) {
                unsigned pend = 0;
#pragma unroll
                for (int i = 0; i < 9; ++i) {
                    int kpos = (w * 9 + i) * 32 + lhi * 8;
                    if (kpos >= 128 && !ok16(vv[i])) pend |= 1u << i;
                }
                while (__builtin_expect(pend != 0, 0)) {
#pragma unroll
                    for (int i = 0; i < 9; ++i)
                        if (pend & (1u << i)) {
                            int kpos = (w * 9 + i) * 32 + lhi * 8;
                            LOAD_SC01(vv[i], hprev + (size_t)row * NH + (kpos - 128));
                        }
                    WAITV0();
#pragma unroll
                    for (int i = 0; i < 9; ++i)
                        if ((pend & (1u << i)) && ok16(vv[i])) pend &= ~(1u << i);
                    if (pend) __builtin_amdgcn_s_sleep(1);
                }
            }
            // ---- MFMA directly on loaded fragments (K-split partials) ----
            f32x4 acc[4] = {};
#pragma unroll
            for (int i = 0; i < 9; ++i) {
                f16x8 av = __builtin_bit_cast(f16x8, vv[i]);
#pragma unroll
                for (int g = 0; g < 4; ++g)
                    acc[g] = MFMA16(av, wr[g * 9 + i], acc[g]);
            }
            __syncthreads();   // B2: gbuf free (prev step's reads done)
#pragma unroll
            for (int g = 0; g < 4; ++g)
#pragma unroll
                for (int r = 0; r < 4; ++r)
                    gbuf[(w * 4 + g) * 272 + (lhi * 4 + r) * 17 + llo] = acc[g][r];
            __syncthreads();   // B3
            // ---- reduce + elementwise + packed publish (threads 0..63) ----
            if (tid < 64) {
                ull pack = 0;
#pragma unroll
                for (int u = 0; u < 4; ++u) {
                    int un = uq + u;
                    float s0 = 0, s1 = 0, s2 = 0, s3 = 0;
#pragma unroll
                    for (int w2 = 0; w2 < 4; ++w2) {
                        s0 += gbuf[(w2 * 4 + 0) * 272 + rb * 17 + un];
                        s1 += gbuf[(w2 * 4 + 1) * 272 + rb * 17 + un];
                        s2 += gbuf[(w2 * 4 + 2) * 272 + rb * 17 + un];
                        s3 += gbuf[(w2 * 4 + 3) * 272 + rb * 17 + un];
                    }
                    float i_ = sigm(s0 + Bi[u]), f_ = sigm(s1 + Bff[u]);
                    float g_ = tanh_(s2 + Bg[u]), o_ = sigm(s3 + Bo[u]);
                    cc[u] = f_ * cc[u] + i_ * g_;
                    float h = o_ * tanh_(cc[u]);
                    unsigned short hb = __builtin_bit_cast(unsigned short, (f16)h);
                    pack |= (ull)hb << (16 * u);
                }
                astore64(h1all + ((size_t)t * NB + bbase + rb) * NH + ubase + uq, pack);
            }
            // ---- ready flag: stores committed (vmcnt0 + barrier) first ----
            WAITV0();
            __syncthreads();   // B4
            if (tid == 0) astore32u(flags1 + (size_t)t * 128 + bid, 1u);
        }
    } else {
        // ====================== R2 (merged P) ======================
        const int b2 = bid - 128, bs = b2 >> 6, us = b2 & 63;
        const int bbase = bs * 16, ubase = us * 16;
        f16x8 wr1[32], wr2[32];   // Wih1, Whh1: wave w owns ks = w*8+i
#pragma unroll
        for (int g = 0; g < 4; ++g)
#pragma unroll
            for (int i = 0; i < 8; ++i) {
                int kpos = (w * 8 + i) * 32 + lhi * 8;
                int col = g * NH + ubase + llo;
                wr1[g * 8 + i] = ld8f(Wih1f + (size_t)col * NH + kpos);
                wr2[g * 8 + i] = ld8f(Whh1f + (size_t)col * NH + kpos);
            }
        float cc[4] = {0.f, 0.f, 0.f, 0.f};
        float Bi[4], Bff[4], Bg[4], Bo[4];
        if (tid < 64) {
#pragma unroll
            for (int u = 0; u < 4; ++u) {
                Bi[u]  = b1[0 * NH + ubase + uq + u];
                Bff[u] = b1[1 * NH + ubase + uq + u];
                Bg[u]  = b1[2 * NH + ubase + uq + u];
                Bo[u]  = b1[3 * NH + ubase + uq + u];
            }
        }
        const int row = bbase + llo;

        for (int t = 0; t < NT; ++t) {
            const f16* A1 = h1all + (size_t)t * NB * NH;
            const f16* A2 = h2all + (size_t)(t - 1) * NB * NH;
            // ---- flag gates: h1[t] (wave0) and h2[t-1] (wave1) ----
            if (w == 0) {
                const unsigned* fp = flags1 + (size_t)t * 128 + bs * 64 + lane;
                int r = 0;
                for (;;) {
                    unsigned v; LOAD_DW_SC01(v, fp); WAITV0();
                    if (__all(v != 0)) break;
                    if (++r > 8) __builtin_amdgcn_s_sleep(1);
                }
            } else if (w == 1 && t > 0) {
                const unsigned* fp = flags2 + (size_t)(t - 1) * 128 + bs * 64 + lane;
                int r = 0;
                for (;;) {
                    unsigned v; LOAD_DW_SC01(v, fp); WAITV0();
                    if (__all(v != 0)) break;
                    if (++r > 8) __builtin_amdgcn_s_sleep(1);
                }
            }
            __syncthreads();   // B1
            // ---- bulk plain loads (L2-shared), sentinel safety net ----
            int4v v1[8], v2[8];
#pragma unroll
            for (int i = 0; i < 8; ++i) {
                int kpos = (w * 8 + i) * 32 + lhi * 8;
                v1[i] = *(const int4v*)(A1 + (size_t)row * NH + kpos);
            }
            if (t > 0) {
#pragma unroll
                for (int i = 0; i < 8; ++i) {
                    int kpos = (w * 8 + i) * 32 + lhi * 8;
                    v2[i] = *(const int4v*)(A2 + (size_t)row * NH + kpos);
                }
            } else {
#pragma unroll
                for (int i = 0; i < 8; ++i) v2[i] = int4v{};
            }
            unsigned p1 = 0, p2 = 0;
#pragma unroll
            for (int i = 0; i < 8; ++i) {
                if (!ok16(v1[i])) p1 |= 1u << i;
                if (t > 0 && !ok16(v2[i])) p2 |= 1u << i;
            }
            while (__builtin_expect((p1 | p2) != 0, 0)) {
#pragma unroll
                for (int i = 0; i < 8; ++i) {
                    int kpos = (w * 8 + i) * 32 + lhi * 8;
                    if (p1 & (1u << i)) LOAD_SC01(v1[i], A1 + (size_t)row * NH + kpos);
                    if (p2 & (1u << i)) LOAD_SC01(v2[i], A2 + (size_t)row * NH + kpos);
                }
                WAITV0();
#pragma unroll
                for (int i = 0; i < 8; ++i) {
                    if ((p1 & (1u << i)) && ok16(v1[i])) p1 &= ~(1u << i);
                    if ((p2 & (1u << i)) && ok16(v2[i])) p2 &= ~(1u << i);
                }
                if (p1 | p2) __builtin_amdgcn_s_sleep(1);
            }

            f32x4 acc[4] = {};
#pragma unroll
            for (int i = 0; i < 8; ++i) {
                f16x8 a1 = __builtin_bit_cast(f16x8, v1[i]);
                f16x8 a2 = __builtin_bit_cast(f16x8, v2[i]);
#pragma unroll
                for (int g = 0; g < 4; ++g) {
                    acc[g] = MFMA16(a1, wr1[g * 8 + i], acc[g]);
                    acc[g] = MFMA16(a2, wr2[g * 8 + i], acc[g]);
                }
            }
            __syncthreads();   // B2
#pragma unroll
            for (int g = 0; g < 4; ++g)
#pragma unroll
                for (int r = 0; r < 4; ++r)
                    gbuf[(w * 4 + g) * 272 + (lhi * 4 + r) * 17 + llo] = acc[g][r];
            __syncthreads();   // B3
            if (tid < 64) {
                ull pack = 0;
#pragma unroll
                for (int u = 0; u < 4; ++u) {
                    int un = uq + u;
                    float s0 = 0, s1 = 0, s2 = 0, s3 = 0;
#pragma unroll
                    for (int w2 = 0; w2 < 4; ++w2) {
                        s0 += gbuf[(w2 * 4 + 0) * 272 + rb * 17 + un];
                        s1 += gbuf[(w2 * 4 + 1) * 272 + rb * 17 + un];
                        s2 += gbuf[(w2 * 4 + 2) * 272 + rb * 17 + un];
                        s3 += gbuf[(w2 * 4 + 3) * 272 + rb * 17 + un];
                    }
                    float i_ = sigm(s0 + Bi[u]), f_ = sigm(s1 + Bff[u]);
                    float g_ = tanh_(s2 + Bg[u]), o_ = sigm(s3 + Bo[u]);
                    cc[u] = f_ * cc[u] + i_ * g_;
                    float h = o_ * tanh_(cc[u]);
                    unsigned short hb = __builtin_bit_cast(unsigned short, (f16)h);
                    pack |= (ull)hb << (16 * u);
                }
                astore64(h2all + ((size_t)t * NB + bbase + rb) * NH + ubase + uq, pack);
            }
            WAITV0();
            __syncthreads();   // B4
            if (tid == 0) astore32u(flags2 + (size_t)t * 128 + b2, 1u);
        }
    }
}

// ---------------------------------------------------------------------------
// Head: out[b][t][o] = h2[b][t][:] @ W_out^T + b_out ; one WG per t
// ---------------------------------------------------------------------------
__device__ __forceinline__ void stage_h(const f16* __restrict__ hsrc, char* smem, int tid) {
    const float4* src = (const float4*)hsrc;
#pragma unroll
    for (int i = 0; i < 16; ++i) {
        int c = i * 256 + tid;
        int off = c * 16;
        int swz = off ^ (((off >> 11) & 7) << 4);
        *(float4*)(smem + swz) = src[c];
    }
}
__device__ __forceinline__ f16x8 afrag(const char* smem, int row, int kk) {
    int off = (row << 11) + kk * 2;
    off ^= ((row & 7) << 4);
    return *(const f16x8*)(smem + off);
}

__global__ __launch_bounds__(256) void head_kernel(
    const f16* __restrict__ h2all, const f16* __restrict__ Wout,
    const float* __restrict__ bout, float* __restrict__ out)
{
    __shared__ __align__(16) char smem[65536];
    int t = blockIdx.x;
    int tid = threadIdx.x;
    int wave = tid >> 6, lane = tid & 63, lhi = lane >> 4, llo = lane & 15;
    stage_h(h2all + (size_t)t * NB * NH, smem, tid);
    __syncthreads();

    f32x4 acc[2][2];
#pragma unroll
    for (int nt = 0; nt < 2; ++nt) {
        int col = wave * 32 + nt * 16 + llo;
        float bb = bout[col];
#pragma unroll
        for (int r = 0; r < 4; ++r) { acc[0][nt][r] = bb; acc[1][nt][r] = bb; }
    }
#pragma unroll 8
    for (int kt = 0; kt < 32; ++kt) {
        int kk = kt * 32 + lhi * 8;
        f16x8 a0 = afrag(smem, llo, kk);
        f16x8 a1 = afrag(smem, 16 + llo, kk);
#pragma unroll
        for (int nt = 0; nt < 2; ++nt) {
            int col = wave * 32 + nt * 16 + llo;
            f16x8 bf = *(const f16x8*)(Wout + (size_t)col * NH + kk);
            acc[0][nt] = MFMA16(a0, bf, acc[0][nt]);
            acc[1][nt] = MFMA16(a1, bf, acc[1][nt]);
        }
    }
#pragma unroll
    for (int nt = 0; nt < 2; ++nt) {
        int col = wave * 32 + nt * 16 + llo;
#pragma unroll
        for (int r = 0; r < 4; ++r) {
            out[(size_t)(lhi * 4 + r) * NT * NO + (size_t)t * NO + col] = acc[0][nt][r];
            out[(size_t)(16 + lhi * 4 + r) * NT * NO + (size_t)t * NO + col] = acc[1][nt][r];
        }
    }
}

extern "C" void kernel_launch(void* const* d_in, const int* in_sizes, int n_in,
                              void* d_out, int out_size, void* d_ws, size_t ws_size,
                              hipStream_t stream)
{
    const float* state = (const float*)d_in[0];
    const float* Wih0f = (const float*)d_in[1];
    const float* Whh0f = (const float*)d_in[2];
    const float* b0    = (const float*)d_in[3];
    const float* Wih1f = (const float*)d_in[4];
    const float* Whh1f = (const float*)d_in[5];
    const float* b1    = (const float*)d_in[6];
    const float* Woutf = (const float*)d_in[7];
    const float* bout  = (const float*)d_in[8];
    float* out = (float*)d_out;
    (void)in_sizes; (void)n_in; (void)out_size; (void)ws_size;

    size_t off = 0;
    char* base = (char*)d_ws;
    auto alloc = [&](size_t bytes) -> void* {
        void* p = base + off;
        off += (bytes + 255) & ~(size_t)255;
        return p;
    };
    f16* state16 = (f16*)alloc((size_t)NB * NT * NI * 2);
    f16* Wout    = (f16*)alloc((size_t)NO * NH * 2);
    f16* h1all   = (f16*)alloc((size_t)NT * NB * NH * 2);
    f16* h2all   = (f16*)alloc((size_t)NT * NB * NH * 2);
    unsigned* flags1 = (unsigned*)alloc((size_t)NT * 128 * 4);
    unsigned* flags2 = (unsigned*)alloc((size_t)NT * 128 * 4);

    convf16<<<(NB * NT * NI + 255) / 256, 256, 0, stream>>>(state, state16, NB * NT * NI);
    convf16<<<(NO * NH + 255) / 256, 256, 0, stream>>>(Woutf, Wout, NO * NH);
    // sentinel-fill h1all+h2all (contiguous); zero flags (contiguous)
    hipMemsetAsync(h1all, 0x7F, (size_t)2 * NT * NB * NH * 2, stream);
    hipMemsetAsync(flags1, 0, (size_t)2 * NT * 128 * 4, stream);

    hipFuncSetAttribute((const void*)persist,
                        hipFuncAttributeMaxDynamicSharedMemorySize, 86016);
    persist<<<256, 256, 86016, stream>>>(Wih0f, Whh0f, b0, Wih1f, Whh1f, b1,
                                         state16, h1all, h2all, flags1, flags2);
    head_kernel<<<NT, 256, 0, stream>>>(h2all, Wout, bout, out);
}

// Round 12
// 3208.330 us; speedup vs baseline: 1.1055x; 1.1055x over previous
//
#include <hip/hip_runtime.h>

#define NB 32
#define NT 512
#define NI 128
#define NH 1024
#define NG 4096
#define NO 128

typedef _Float16 f16;
typedef _Float16 f16x8 __attribute__((ext_vector_type(8)));
typedef float f32x4 __attribute__((ext_vector_type(4)));
typedef int int4v __attribute__((ext_vector_type(4)));
typedef unsigned long long ull;

#define MFMA16(a, b, c) __builtin_amdgcn_mfma_f32_16x16x32_f16(a, b, c, 0, 0, 0)
#define SENTD 0x7F7F7F7Fu

__device__ __forceinline__ float sigm(float x) { return 1.f / (1.f + __expf(-x)); }
__device__ __forceinline__ float tanh_(float x) {
    float a = fabsf(x);
    float e = __expf(-2.f * a);
    float r = (1.f - e) / (1.f + e);
    return x < 0.f ? -r : r;
}
// valid when NO dword equals the 0x7F7F7F7F sentinel (f16 NaN pair; |h|<1
// so real packed h never encodes as it)
__device__ __forceinline__ bool ok16(int4v v) {
    return v.x != (int)SENTD && v.y != (int)SENTD && v.z != (int)SENTD && v.w != (int)SENTD;
}
__device__ __forceinline__ void astore32u(void* p, unsigned v) {
    __hip_atomic_store((unsigned*)p, v, __ATOMIC_RELAXED, __HIP_MEMORY_SCOPE_AGENT);
}
__device__ __forceinline__ f16x8 ld8f(const float* s) {
    float4 x0 = *(const float4*)s, x1 = *(const float4*)(s + 4);
    f16x8 v;
    v[0] = (f16)x0.x; v[1] = (f16)x0.y; v[2] = (f16)x0.z; v[3] = (f16)x0.w;
    v[4] = (f16)x1.x; v[5] = (f16)x1.y; v[6] = (f16)x1.z; v[7] = (f16)x1.w;
    return v;
}
// 16B load, L1+L2-bypass (L3-direct): always coherent with agent-atomic
// stores from any XCD; no fences, no stale-line hazard.
#define LOAD_SC01(dst, addr) \
    asm volatile("global_load_dwordx4 %0, %1, off sc0 sc1" : "=v"(dst) : "v"(addr))
#define WAITV0() do { asm volatile("s_waitcnt vmcnt(0)" ::: "memory"); \
                      __builtin_amdgcn_sched_barrier(0); } while (0)

__global__ void convf16(const float* __restrict__ src, f16* __restrict__ dst, int n) {
    int i = blockIdx.x * blockDim.x + threadIdx.x;
    if (i < n) dst[i] = (f16)src[i];
}

// ---------------------------------------------------------------------------
// Persistent pipeline (R8 structure + prefetch-at-bottom + 128-thr epilogue):
// 256 WGs x 256 thr, 1 WG/CU (forced by 84KB dyn LDS).
//  bid [0,128)   R1: layer-1 step, (16 batch, 16 units)/CU, K=1152 (state|h1).
//  bid [128,256) R2: layer-2 step + input proj, (16 batch, 16 units)/CU,
//                two K=1024 matmuls (h1[t]@Wih1 + h2[t-1]@Whh1).
// Weights in VGPRs (K split across 4 waves, 4 gates). Producers publish
// packed 4B agent-atomic stores (L3). Consumers bulk-read h with SC01 16B
// loads (L3-direct, always fresh), sentinel-validate per dword, retry only
// pending fragments. Next-step loads are ISSUED at loop bottom right after
// publish so the first poll RT overlaps the loop tail. No flags, no fences,
// no rings -> deadlock-impossible. LDS holds the padded K-reduction buffer.
// ---------------------------------------------------------------------------
extern "C" __global__ __launch_bounds__(256, 1) void persist(
    const float* __restrict__ Wih0f, const float* __restrict__ Whh0f, const float* __restrict__ b0,
    const float* __restrict__ Wih1f, const float* __restrict__ Whh1f, const float* __restrict__ b1,
    const f16* __restrict__ state16,
    f16* __restrict__ h1all,      // [NT][NB][NH], 0x7F-filled
    f16* __restrict__ h2all)      // [NT][NB][NH], 0x7F-filled
{
    extern __shared__ char smem[];
    float* gbuf = (float*)smem;   // [16][16*17] f32 partials, +17 pad
    const int bid = blockIdx.x;
    const int tid = threadIdx.x;
    const int w = tid >> 6;
    const int lane = tid & 63;
    const int llo = lane & 15;
    const int lhi = lane >> 4;
    const int eb = tid >> 3;        // epilogue: batch row (threads 0..127)
    const int up = (tid & 7) * 2;   // epilogue: unit-pair base

    if (bid < 128) {
        // ============================ R1 ============================
        const int bs = bid >> 6, us = bid & 63;
        const int bbase = bs * 16, ubase = us * 16;
        const int row = bbase + llo;
        // weights: wave w owns ks = w*9+i (K=1152), 4 gate-column blocks
        f16x8 wr[36];
#pragma unroll
        for (int g = 0; g < 4; ++g)
#pragma unroll
            for (int i = 0; i < 9; ++i) {
                int kpos = (w * 9 + i) * 32 + lhi * 8;
                int col = g * NH + ubase + llo;
                const float* s = (kpos < 128) ? (Wih0f + (size_t)col * NI + kpos)
                                              : (Whh0f + (size_t)col * NH + (kpos - 128));
                wr[g * 9 + i] = ld8f(s);
            }
        float cc2[2] = {0.f, 0.f};
        float Bi[2], Bff[2], Bg[2], Bo[2];
        if (tid < 128) {
#pragma unroll
            for (int j = 0; j < 2; ++j) {
                Bi[j]  = b0[0 * NH + ubase + up + j];
                Bff[j] = b0[1 * NH + ubase + up + j];
                Bg[j]  = b0[2 * NH + ubase + up + j];
                Bo[j]  = b0[3 * NH + ubase + up + j];
            }
        }

        int4v vv[9];
        auto issue1 = [&](int tn) {
#pragma unroll
            for (int i = 0; i < 9; ++i) {
                int kpos = (w * 9 + i) * 32 + lhi * 8;
                if (kpos < 128)
                    vv[i] = *(const int4v*)(state16 + ((size_t)row * NT + tn) * NI + kpos);
                else if (tn > 0) {
                    LOAD_SC01(vv[i], h1all + (size_t)(tn - 1) * NB * NH
                                     + (size_t)row * NH + (kpos - 128));
                } else
                    vv[i] = int4v{};
            }
        };
        issue1(0);

        for (int t = 0; t < NT; ++t) {
            const f16* hprev = h1all + (size_t)(t - 1) * NB * NH;
            WAITV0();
            if (t > 0) {
                unsigned pend = 0;
#pragma unroll
                for (int i = 0; i < 9; ++i) {
                    int kpos = (w * 9 + i) * 32 + lhi * 8;
                    if (kpos >= 128 && !ok16(vv[i])) pend |= 1u << i;
                }
                while (__builtin_expect(pend != 0, 0)) {
#pragma unroll
                    for (int i = 0; i < 9; ++i)
                        if (pend & (1u << i)) {
                            int kpos = (w * 9 + i) * 32 + lhi * 8;
                            LOAD_SC01(vv[i], hprev + (size_t)row * NH + (kpos - 128));
                        }
                    WAITV0();
#pragma unroll
                    for (int i = 0; i < 9; ++i)
                        if ((pend & (1u << i)) && ok16(vv[i])) pend &= ~(1u << i);
                    if (pend) __builtin_amdgcn_s_sleep(1);
                }
            }
            // ---- MFMA directly on loaded fragments (K-split partials) ----
            f32x4 acc[4] = {};
#pragma unroll
            for (int i = 0; i < 9; ++i) {
                f16x8 av = __builtin_bit_cast(f16x8, vv[i]);
#pragma unroll
                for (int g = 0; g < 4; ++g)
                    acc[g] = MFMA16(av, wr[g * 9 + i], acc[g]);
            }
            __syncthreads();   // gbuf free (prev step's reads done)
#pragma unroll
            for (int g = 0; g < 4; ++g)
#pragma unroll
                for (int r = 0; r < 4; ++r)
                    gbuf[(w * 4 + g) * 272 + (lhi * 4 + r) * 17 + llo] = acc[g][r];
            __syncthreads();
            // ---- reduce + elementwise + dword publish (threads 0..127) ----
            if (tid < 128) {
                unsigned pk = 0;
#pragma unroll
                for (int j = 0; j < 2; ++j) {
                    int un = up + j;
                    float s0 = 0, s1 = 0, s2 = 0, s3 = 0;
#pragma unroll
                    for (int w2 = 0; w2 < 4; ++w2) {
                        s0 += gbuf[(w2 * 4 + 0) * 272 + eb * 17 + un];
                        s1 += gbuf[(w2 * 4 + 1) * 272 + eb * 17 + un];
                        s2 += gbuf[(w2 * 4 + 2) * 272 + eb * 17 + un];
                        s3 += gbuf[(w2 * 4 + 3) * 272 + eb * 17 + un];
                    }
                    float i_ = sigm(s0 + Bi[j]), f_ = sigm(s1 + Bff[j]);
                    float g_ = tanh_(s2 + Bg[j]), o_ = sigm(s3 + Bo[j]);
                    cc2[j] = f_ * cc2[j] + i_ * g_;
                    float h = o_ * tanh_(cc2[j]);
                    unsigned short hb = __builtin_bit_cast(unsigned short, (f16)h);
                    pk |= (unsigned)hb << (16 * j);
                }
                astore32u(h1all + ((size_t)t * NB + bbase + eb) * NH + ubase + up, pk);
            }
            // ---- prefetch next step (first poll overlaps loop tail) ----
            if (t + 1 < NT) issue1(t + 1);
        }
    } else {
        // ====================== R2 (merged P) ======================
        const int b2 = bid - 128, bs = b2 >> 6, us = b2 & 63;
        const int bbase = bs * 16, ubase = us * 16;
        const int row = bbase + llo;
        f16x8 wr1[32], wr2[32];   // Wih1, Whh1: wave w owns ks = w*8+i
#pragma unroll
        for (int g = 0; g < 4; ++g)
#pragma unroll
            for (int i = 0; i < 8; ++i) {
                int kpos = (w * 8 + i) * 32 + lhi * 8;
                int col = g * NH + ubase + llo;
                wr1[g * 8 + i] = ld8f(Wih1f + (size_t)col * NH + kpos);
                wr2[g * 8 + i] = ld8f(Whh1f + (size_t)col * NH + kpos);
            }
        float cc2[2] = {0.f, 0.f};
        float Bi[2], Bff[2], Bg[2], Bo[2];
        if (tid < 128) {
#pragma unroll
            for (int j = 0; j < 2; ++j) {
                Bi[j]  = b1[0 * NH + ubase + up + j];
                Bff[j] = b1[1 * NH + ubase + up + j];
                Bg[j]  = b1[2 * NH + ubase + up + j];
                Bo[j]  = b1[3 * NH + ubase + up + j];
            }
        }

        int4v v1[8], v2[8];
        auto issueV2 = [&](int tn) {   // h2[tn-1] (the critical recurrence spin)
#pragma unroll
            for (int i = 0; i < 8; ++i) {
                int kpos = (w * 8 + i) * 32 + lhi * 8;
                if (tn > 0) {
                    LOAD_SC01(v2[i], h2all + (size_t)(tn - 1) * NB * NH
                                     + (size_t)row * NH + kpos);
                } else
                    v2[i] = int4v{};
            }
        };
        issueV2(0);

        for (int t = 0; t < NT; ++t) {
            const f16* A1 = h1all + (size_t)t * NB * NH;
            const f16* A2 = h2all + (size_t)(t - 1) * NB * NH;
            // issue v1 (h1[t], usually already published by R1 running ahead)
#pragma unroll
            for (int i = 0; i < 8; ++i) {
                int kpos = (w * 8 + i) * 32 + lhi * 8;
                LOAD_SC01(v1[i], A1 + (size_t)row * NH + kpos);
            }
            WAITV0();
            unsigned p1 = 0, p2 = 0;
#pragma unroll
            for (int i = 0; i < 8; ++i) {
                if (!ok16(v1[i])) p1 |= 1u << i;
                if (t > 0 && !ok16(v2[i])) p2 |= 1u << i;
            }
            while (__builtin_expect((p1 | p2) != 0, 0)) {
#pragma unroll
                for (int i = 0; i < 8; ++i) {
                    int kpos = (w * 8 + i) * 32 + lhi * 8;
                    if (p1 & (1u << i)) LOAD_SC01(v1[i], A1 + (size_t)row * NH + kpos);
                    if (p2 & (1u << i)) LOAD_SC01(v2[i], A2 + (size_t)row * NH + kpos);
                }
                WAITV0();
#pragma unroll
                for (int i = 0; i < 8; ++i) {
                    if ((p1 & (1u << i)) && ok16(v1[i])) p1 &= ~(1u << i);
                    if ((p2 & (1u << i)) && ok16(v2[i])) p2 &= ~(1u << i);
                }
                if (p1 | p2) __builtin_amdgcn_s_sleep(1);
            }

            f32x4 acc[4] = {};
#pragma unroll
            for (int i = 0; i < 8; ++i) {
                f16x8 a1 = __builtin_bit_cast(f16x8, v1[i]);
                f16x8 a2 = __builtin_bit_cast(f16x8, v2[i]);
#pragma unroll
                for (int g = 0; g < 4; ++g) {
                    acc[g] = MFMA16(a1, wr1[g * 8 + i], acc[g]);
                    acc[g] = MFMA16(a2, wr2[g * 8 + i], acc[g]);
                }
            }
            __syncthreads();
#pragma unroll
            for (int g = 0; g < 4; ++g)
#pragma unroll
                for (int r = 0; r < 4; ++r)
                    gbuf[(w * 4 + g) * 272 + (lhi * 4 + r) * 17 + llo] = acc[g][r];
            __syncthreads();
            if (tid < 128) {
                unsigned pk = 0;
#pragma unroll
                for (int j = 0; j < 2; ++j) {
                    int un = up + j;
                    float s0 = 0, s1 = 0, s2 = 0, s3 = 0;
#pragma unroll
                    for (int w2 = 0; w2 < 4; ++w2) {
                        s0 += gbuf[(w2 * 4 + 0) * 272 + eb * 17 + un];
                        s1 += gbuf[(w2 * 4 + 1) * 272 + eb * 17 + un];
                        s2 += gbuf[(w2 * 4 + 2) * 272 + eb * 17 + un];
                        s3 += gbuf[(w2 * 4 + 3) * 272 + eb * 17 + un];
                    }
                    float i_ = sigm(s0 + Bi[j]), f_ = sigm(s1 + Bff[j]);
                    float g_ = tanh_(s2 + Bg[j]), o_ = sigm(s3 + Bo[j]);
                    cc2[j] = f_ * cc2[j] + i_ * g_;
                    float h = o_ * tanh_(cc2[j]);
                    unsigned short hb = __builtin_bit_cast(unsigned short, (f16)h);
                    pk |= (unsigned)hb << (16 * j);
                }
                astore32u(h2all + ((size_t)t * NB + bbase + eb) * NH + ubase + up, pk);
            }
            if (t + 1 < NT) issueV2(t + 1);
        }
    }
}

// ---------------------------------------------------------------------------
// Head: out[b][t][o] = h2[b][t][:] @ W_out^T + b_out ; one WG per t
// ---------------------------------------------------------------------------
__device__ __forceinline__ void stage_h(const f16* __restrict__ hsrc, char* smem, int tid) {
    const float4* src = (const float4*)hsrc;
#pragma unroll
    for (int i = 0; i < 16; ++i) {
        int c = i * 256 + tid;
        int off = c * 16;
        int swz = off ^ (((off >> 11) & 7) << 4);
        *(float4*)(smem + swz) = src[c];
    }
}
__device__ __forceinline__ f16x8 afrag(const char* smem, int row, int kk) {
    int off = (row << 11) + kk * 2;
    off ^= ((row & 7) << 4);
    return *(const f16x8*)(smem + off);
}

__global__ __launch_bounds__(256) void head_kernel(
    const f16* __restrict__ h2all, const f16* __restrict__ Wout,
    const float* __restrict__ bout, float* __restrict__ out)
{
    __shared__ __align__(16) char smem[65536];
    int t = blockIdx.x;
    int tid = threadIdx.x;
    int wave = tid >> 6, lane = tid & 63, lhi = lane >> 4, llo = lane & 15;
    stage_h(h2all + (size_t)t * NB * NH, smem, tid);
    __syncthreads();

    f32x4 acc[2][2];
#pragma unroll
    for (int nt = 0; nt < 2; ++nt) {
        int col = wave * 32 + nt * 16 + llo;
        float bb = bout[col];
#pragma unroll
        for (int r = 0; r < 4; ++r) { acc[0][nt][r] = bb; acc[1][nt][r] = bb; }
    }
#pragma unroll 8
    for (int kt = 0; kt < 32; ++kt) {
        int kk = kt * 32 + lhi * 8;
        f16x8 a0 = afrag(smem, llo, kk);
        f16x8 a1 = afrag(smem, 16 + llo, kk);
#pragma unroll
        for (int nt = 0; nt < 2; ++nt) {
            int col = wave * 32 + nt * 16 + llo;
            f16x8 bf = *(const f16x8*)(Wout + (size_t)col * NH + kk);
            acc[0][nt] = MFMA16(a0, bf, acc[0][nt]);
            acc[1][nt] = MFMA16(a1, bf, acc[1][nt]);
        }
    }
#pragma unroll
    for (int nt = 0; nt < 2; ++nt) {
        int col = wave * 32 + nt * 16 + llo;
#pragma unroll
        for (int r = 0; r < 4; ++r) {
            out[(size_t)(lhi * 4 + r) * NT * NO + (size_t)t * NO + col] = acc[0][nt][r];
            out[(size_t)(16 + lhi * 4 + r) * NT * NO + (size_t)t * NO + col] = acc[1][nt][r];
        }
    }
}

extern "C" void kernel_launch(void* const* d_in, const int* in_sizes, int n_in,
                              void* d_out, int out_size, void* d_ws, size_t ws_size,
                              hipStream_t stream)
{
    const float* state = (const float*)d_in[0];
    const float* Wih0f = (const float*)d_in[1];
    const float* Whh0f = (const float*)d_in[2];
    const float* b0    = (const float*)d_in[3];
    const float* Wih1f = (const float*)d_in[4];
    const float* Whh1f = (const float*)d_in[5];
    const float* b1    = (const float*)d_in[6];
    const float* Woutf = (const float*)d_in[7];
    const float* bout  = (const float*)d_in[8];
    float* out = (float*)d_out;
    (void)in_sizes; (void)n_in; (void)out_size; (void)ws_size;

    size_t off = 0;
    char* base = (char*)d_ws;
    auto alloc = [&](size_t bytes) -> void* {
        void* p = base + off;
        off += (bytes + 255) & ~(size_t)255;
        return p;
    };
    f16* state16 = (f16*)alloc((size_t)NB * NT * NI * 2);
    f16* Wout    = (f16*)alloc((size_t)NO * NH * 2);
    f16* h1all   = (f16*)alloc((size_t)NT * NB * NH * 2);
    f16* h2all   = (f16*)alloc((size_t)NT * NB * NH * 2);

    convf16<<<(NB * NT * NI + 255) / 256, 256, 0, stream>>>(state, state16, NB * NT * NI);
    convf16<<<(NO * NH + 255) / 256, 256, 0, stream>>>(Woutf, Wout, NO * NH);
    // sentinel-fill h1all+h2all (contiguous) — consumers bypass L2 (SC01)
    hipMemsetAsync(h1all, 0x7F, (size_t)2 * NT * NB * NH * 2, stream);

    hipFuncSetAttribute((const void*)persist,
                        hipFuncAttributeMaxDynamicSharedMemorySize, 86016);
    persist<<<256, 256, 86016, stream>>>(Wih0f, Whh0f, b0, Wih1f, Whh1f, b1,
                                         state16, h1all, h2all);
    head_kernel<<<NT, 256, 0, stream>>>(h2all, Wout, bout, out);
}

// Round 13
// 2852.930 us; speedup vs baseline: 1.2432x; 1.1246x over previous
//
#include <hip/hip_runtime.h>

#define NB 32
#define NT 512
#define NI 128
#define NH 1024
#define NG 4096
#define NO 128

typedef _Float16 f16;
typedef _Float16 f16x8 __attribute__((ext_vector_type(8)));
typedef float f32x4 __attribute__((ext_vector_type(4)));
typedef int int4v __attribute__((ext_vector_type(4)));
typedef unsigned long long ull;

#define MFMA16(a, b, c) __builtin_amdgcn_mfma_f32_16x16x32_f16(a, b, c, 0, 0, 0)
#define SENTD 0x7F7F7F7Fu

__device__ __forceinline__ float sigm(float x) { return 1.f / (1.f + __expf(-x)); }
__device__ __forceinline__ float tanh_(float x) {
    float a = fabsf(x);
    float e = __expf(-2.f * a);
    float r = (1.f - e) / (1.f + e);
    return x < 0.f ? -r : r;
}
// valid when NO dword equals the 0x7F7F7F7F sentinel (f16 NaN pair; |h|<1
// so real packed h never encodes as it)
__device__ __forceinline__ bool ok16(int4v v) {
    return v.x != (int)SENTD && v.y != (int)SENTD && v.z != (int)SENTD && v.w != (int)SENTD;
}
__device__ __forceinline__ void astore64(void* p, ull v) {
    __hip_atomic_store((ull*)p, v, __ATOMIC_RELAXED, __HIP_MEMORY_SCOPE_AGENT);
}
__device__ __forceinline__ f16x8 ld8f(const float* s) {
    float4 x0 = *(const float4*)s, x1 = *(const float4*)(s + 4);
    f16x8 v;
    v[0] = (f16)x0.x; v[1] = (f16)x0.y; v[2] = (f16)x0.z; v[3] = (f16)x0.w;
    v[4] = (f16)x1.x; v[5] = (f16)x1.y; v[6] = (f16)x1.z; v[7] = (f16)x1.w;
    return v;
}
// 16B load, L1+L2-bypass (L3-direct): always coherent with agent-atomic
// stores from any XCD; no fences, no stale-line hazard.
#define LOAD_SC01(dst, addr) \
    asm volatile("global_load_dwordx4 %0, %1, off sc0 sc1" : "=v"(dst) : "v"(addr))
#define WAITV0() do { asm volatile("s_waitcnt vmcnt(0)" ::: "memory"); \
                      __builtin_amdgcn_sched_barrier(0); } while (0)
// wait until at most 8 VMEM ops outstanding (retires the older v1 batch)
#define WAITV8() do { asm volatile("s_waitcnt vmcnt(8)" ::: "memory"); \
                      __builtin_amdgcn_sched_barrier(0); } while (0)

__global__ void convf16(const float* __restrict__ src, f16* __restrict__ dst, int n) {
    int i = blockIdx.x * blockDim.x + threadIdx.x;
    if (i < n) dst[i] = (f16)src[i];
}

// ---------------------------------------------------------------------------
// Persistent pipeline (R8 structure; R2 overlaps v1-MFMAs with the v2 spin):
// 256 WGs x 256 thr, 1 WG/CU (forced by 84KB dyn LDS).
//  bid [0,128)   R1: layer-1 step, (16 batch, 16 units)/CU, K=1152 (state|h1).
//  bid [128,256) R2: layer-2 step + input proj, (16 batch, 16 units)/CU,
//                two K=1024 matmuls (h1[t]@Wih1 + h2[t-1]@Whh1).
// Weights in VGPRs (K split across 4 waves, 4 gates). A-fragments go straight
// from global loads into MFMA. Producers publish packed 8B agent-scope
// atomic stores (L3-resident). Consumers bulk-read h with SC01 16B loads
// (L3-direct, always fresh); any fragment still sentinel is re-read with the
// same SC01 loads. R2 waits vmcnt(8) to validate v1 early and runs its 32
// v1-MFMAs while the critical h2[t-1] loads are still in flight. No flags,
// no fences, no rings -> deadlock-impossible. LDS: padded K-reduction buffer.
// ---------------------------------------------------------------------------
extern "C" __global__ __launch_bounds__(256, 1) void persist(
    const float* __restrict__ Wih0f, const float* __restrict__ Whh0f, const float* __restrict__ b0,
    const float* __restrict__ Wih1f, const float* __restrict__ Whh1f, const float* __restrict__ b1,
    const f16* __restrict__ state16,
    f16* __restrict__ h1all,      // [NT][NB][NH], 0x7F-filled
    f16* __restrict__ h2all)      // [NT][NB][NH], 0x7F-filled
{
    extern __shared__ char smem[];
    float* gbuf = (float*)smem;   // [16][16*17] f32 partials, +17 pad
    const int bid = blockIdx.x;
    const int tid = threadIdx.x;
    const int w = tid >> 6;
    const int lane = tid & 63;
    const int llo = lane & 15;
    const int lhi = lane >> 4;
    const int rb = tid >> 2;        // elementwise: batch row (threads 0..63)
    const int uq = (tid & 3) * 4;   // elementwise: unit quad base

    if (bid < 128) {
        // ============================ R1 ============================
        const int bs = bid >> 6, us = bid & 63;
        const int bbase = bs * 16, ubase = us * 16;
        // weights: wave w owns ks = w*9+i (K=1152), 4 gate-column blocks
        f16x8 wr[36];
#pragma unroll
        for (int g = 0; g < 4; ++g)
#pragma unroll
            for (int i = 0; i < 9; ++i) {
                int kpos = (w * 9 + i) * 32 + lhi * 8;
                int col = g * NH + ubase + llo;
                const float* s = (kpos < 128) ? (Wih0f + (size_t)col * NI + kpos)
                                              : (Whh0f + (size_t)col * NH + (kpos - 128));
                wr[g * 9 + i] = ld8f(s);
            }
        float cc[4] = {0.f, 0.f, 0.f, 0.f};
        float Bi[4], Bff[4], Bg[4], Bo[4];
        if (tid < 64) {
#pragma unroll
            for (int u = 0; u < 4; ++u) {
                Bi[u]  = b0[0 * NH + ubase + uq + u];
                Bff[u] = b0[1 * NH + ubase + uq + u];
                Bg[u]  = b0[2 * NH + ubase + uq + u];
                Bo[u]  = b0[3 * NH + ubase + uq + u];
            }
        }

        for (int t = 0; t < NT; ++t) {
            const f16* hprev = h1all + (size_t)(t - 1) * NB * NH;
            const int row = bbase + llo;
            // ---- bulk SC01 loads (L3-direct), sentinel-validate, SC01 retry ----
            int4v vv[9];
#pragma unroll
            for (int i = 0; i < 9; ++i) {
                int kpos = (w * 9 + i) * 32 + lhi * 8;
                if (kpos < 128)
                    vv[i] = *(const int4v*)(state16 + ((size_t)row * NT + t) * NI + kpos);
                else if (t > 0) {
                    LOAD_SC01(vv[i], hprev + (size_t)row * NH + (kpos - 128));
                } else
                    vv[i] = int4v{};
            }
            if (t > 0) {
                WAITV0();
                unsigned pend = 0;
#pragma unroll
                for (int i = 0; i < 9; ++i) {
                    int kpos = (w * 9 + i) * 32 + lhi * 8;
                    if (kpos >= 128 && !ok16(vv[i])) pend |= 1u << i;
                }
                while (__builtin_expect(pend != 0, 0)) {
#pragma unroll
                    for (int i = 0; i < 9; ++i)
                        if (pend & (1u << i)) {
                            int kpos = (w * 9 + i) * 32 + lhi * 8;
                            LOAD_SC01(vv[i], hprev + (size_t)row * NH + (kpos - 128));
                        }
                    WAITV0();
#pragma unroll
                    for (int i = 0; i < 9; ++i)
                        if ((pend & (1u << i)) && ok16(vv[i])) pend &= ~(1u << i);
                    if (pend) __builtin_amdgcn_s_sleep(1);
                }
            }
            // ---- MFMA directly on loaded fragments (K-split partials) ----
            f32x4 acc[4] = {};
#pragma unroll
            for (int i = 0; i < 9; ++i) {
                f16x8 av = __builtin_bit_cast(f16x8, vv[i]);
#pragma unroll
                for (int g = 0; g < 4; ++g)
                    acc[g] = MFMA16(av, wr[g * 9 + i], acc[g]);
            }
            __syncthreads();   // gbuf free (prev step's reads done)
#pragma unroll
            for (int g = 0; g < 4; ++g)
#pragma unroll
                for (int r = 0; r < 4; ++r)
                    gbuf[(w * 4 + g) * 272 + (lhi * 4 + r) * 17 + llo] = acc[g][r];
            __syncthreads();
            // ---- reduce + elementwise + packed publish (threads 0..63) ----
            if (tid < 64) {
                ull pack = 0;
#pragma unroll
                for (int u = 0; u < 4; ++u) {
                    int un = uq + u;
                    float s0 = 0, s1 = 0, s2 = 0, s3 = 0;
#pragma unroll
                    for (int w2 = 0; w2 < 4; ++w2) {
                        s0 += gbuf[(w2 * 4 + 0) * 272 + rb * 17 + un];
                        s1 += gbuf[(w2 * 4 + 1) * 272 + rb * 17 + un];
                        s2 += gbuf[(w2 * 4 + 2) * 272 + rb * 17 + un];
                        s3 += gbuf[(w2 * 4 + 3) * 272 + rb * 17 + un];
                    }
                    float i_ = sigm(s0 + Bi[u]), f_ = sigm(s1 + Bff[u]);
                    float g_ = tanh_(s2 + Bg[u]), o_ = sigm(s3 + Bo[u]);
                    cc[u] = f_ * cc[u] + i_ * g_;
                    float h = o_ * tanh_(cc[u]);
                    unsigned short hb = __builtin_bit_cast(unsigned short, (f16)h);
                    pack |= (ull)hb << (16 * u);
                }
                astore64(h1all + ((size_t)t * NB + bbase + rb) * NH + ubase + uq, pack);
            }
        }
    } else {
        // ====================== R2 (merged P) ======================
        const int b2 = bid - 128, bs = b2 >> 6, us = b2 & 63;
        const int bbase = bs * 16, ubase = us * 16;
        f16x8 wr1[32], wr2[32];   // Wih1, Whh1: wave w owns ks = w*8+i
#pragma unroll
        for (int g = 0; g < 4; ++g)
#pragma unroll
            for (int i = 0; i < 8; ++i) {
                int kpos = (w * 8 + i) * 32 + lhi * 8;
                int col = g * NH + ubase + llo;
                wr1[g * 8 + i] = ld8f(Wih1f + (size_t)col * NH + kpos);
                wr2[g * 8 + i] = ld8f(Whh1f + (size_t)col * NH + kpos);
            }
        float cc[4] = {0.f, 0.f, 0.f, 0.f};
        float Bi[4], Bff[4], Bg[4], Bo[4];
        if (tid < 64) {
#pragma unroll
            for (int u = 0; u < 4; ++u) {
                Bi[u]  = b1[0 * NH + ubase + uq + u];
                Bff[u] = b1[1 * NH + ubase + uq + u];
                Bg[u]  = b1[2 * NH + ubase + uq + u];
                Bo[u]  = b1[3 * NH + ubase + uq + u];
            }
        }
        const int row = bbase + llo;

        for (int t = 0; t < NT; ++t) {
            const f16* A1 = h1all + (size_t)t * NB * NH;
            const f16* A2 = h2all + (size_t)(t - 1) * NB * NH;
            int4v v1[8], v2[8];
            // issue v1 (usually ready: R1 runs ahead), then v2 (critical spin)
#pragma unroll
            for (int i = 0; i < 8; ++i) {
                int kpos = (w * 8 + i) * 32 + lhi * 8;
                LOAD_SC01(v1[i], A1 + (size_t)row * NH + kpos);
            }
            if (t > 0) {
#pragma unroll
                for (int i = 0; i < 8; ++i) {
                    int kpos = (w * 8 + i) * 32 + lhi * 8;
                    LOAD_SC01(v2[i], A2 + (size_t)row * NH + kpos);
                }
                WAITV8();   // retire v1 batch only; v2 still in flight
            } else {
#pragma unroll
                for (int i = 0; i < 8; ++i) v2[i] = int4v{};
                WAITV0();
            }
            // ---- validate v1 (retry rare), then run v1 MFMAs under v2 flight ----
            unsigned p1 = 0;
#pragma unroll
            for (int i = 0; i < 8; ++i)
                if (!ok16(v1[i])) p1 |= 1u << i;
            while (__builtin_expect(p1 != 0, 0)) {
#pragma unroll
                for (int i = 0; i < 8; ++i)
                    if (p1 & (1u << i)) {
                        int kpos = (w * 8 + i) * 32 + lhi * 8;
                        LOAD_SC01(v1[i], A1 + (size_t)row * NH + kpos);
                    }
                WAITV0();
#pragma unroll
                for (int i = 0; i < 8; ++i)
                    if ((p1 & (1u << i)) && ok16(v1[i])) p1 &= ~(1u << i);
                if (p1) __builtin_amdgcn_s_sleep(1);
            }
            f32x4 acc[4] = {};
#pragma unroll
            for (int i = 0; i < 8; ++i) {
                f16x8 a1 = __builtin_bit_cast(f16x8, v1[i]);
#pragma unroll
                for (int g = 0; g < 4; ++g)
                    acc[g] = MFMA16(a1, wr1[g * 8 + i], acc[g]);
            }
            // ---- now the critical v2 (h2[t-1]) spin + MFMAs ----
            WAITV0();
            unsigned p2 = 0;
            if (t > 0) {
#pragma unroll
                for (int i = 0; i < 8; ++i)
                    if (!ok16(v2[i])) p2 |= 1u << i;
            }
            while (__builtin_expect(p2 != 0, 0)) {
#pragma unroll
                for (int i = 0; i < 8; ++i)
                    if (p2 & (1u << i)) {
                        int kpos = (w * 8 + i) * 32 + lhi * 8;
                        LOAD_SC01(v2[i], A2 + (size_t)row * NH + kpos);
                    }
                WAITV0();
#pragma unroll
                for (int i = 0; i < 8; ++i)
                    if ((p2 & (1u << i)) && ok16(v2[i])) p2 &= ~(1u << i);
                if (p2) __builtin_amdgcn_s_sleep(1);
            }
#pragma unroll
            for (int i = 0; i < 8; ++i) {
                f16x8 a2 = __builtin_bit_cast(f16x8, v2[i]);
#pragma unroll
                for (int g = 0; g < 4; ++g)
                    acc[g] = MFMA16(a2, wr2[g * 8 + i], acc[g]);
            }
            __syncthreads();
#pragma unroll
            for (int g = 0; g < 4; ++g)
#pragma unroll
                for (int r = 0; r < 4; ++r)
                    gbuf[(w * 4 + g) * 272 + (lhi * 4 + r) * 17 + llo] = acc[g][r];
            __syncthreads();
            if (tid < 64) {
                ull pack = 0;
#pragma unroll
                for (int u = 0; u < 4; ++u) {
                    int un = uq + u;
                    float s0 = 0, s1 = 0, s2 = 0, s3 = 0;
#pragma unroll
                    for (int w2 = 0; w2 < 4; ++w2) {
                        s0 += gbuf[(w2 * 4 + 0) * 272 + rb * 17 + un];
                        s1 += gbuf[(w2 * 4 + 1) * 272 + rb * 17 + un];
                        s2 += gbuf[(w2 * 4 + 2) * 272 + rb * 17 + un];
                        s3 += gbuf[(w2 * 4 + 3) * 272 + rb * 17 + un];
                    }
                    float i_ = sigm(s0 + Bi[u]), f_ = sigm(s1 + Bff[u]);
                    float g_ = tanh_(s2 + Bg[u]), o_ = sigm(s3 + Bo[u]);
                    cc[u] = f_ * cc[u] + i_ * g_;
                    float h = o_ * tanh_(cc[u]);
                    unsigned short hb = __builtin_bit_cast(unsigned short, (f16)h);
                    pack |= (ull)hb << (16 * u);
                }
                astore64(h2all + ((size_t)t * NB + bbase + rb) * NH + ubase + uq, pack);
            }
        }
    }
}

// ---------------------------------------------------------------------------
// Head: out[b][t][o] = h2[b][t][:] @ W_out^T + b_out ; one WG per t
// ---------------------------------------------------------------------------
__device__ __forceinline__ void stage_h(const f16* __restrict__ hsrc, char* smem, int tid) {
    const float4* src = (const float4*)hsrc;
#pragma unroll
    for (int i = 0; i < 16; ++i) {
        int c = i * 256 + tid;
        int off = c * 16;
        int swz = off ^ (((off >> 11) & 7) << 4);
        *(float4*)(smem + swz) = src[c];
    }
}
__device__ __forceinline__ f16x8 afrag(const char* smem, int row, int kk) {
    int off = (row << 11) + kk * 2;
    off ^= ((row & 7) << 4);
    return *(const f16x8*)(smem + off);
}

__global__ __launch_bounds__(256) void head_kernel(
    const f16* __restrict__ h2all, const f16* __restrict__ Wout,
    const float* __restrict__ bout, float* __restrict__ out)
{
    __shared__ __align__(16) char smem[65536];
    int t = blockIdx.x;
    int tid = threadIdx.x;
    int wave = tid >> 6, lane = tid & 63, lhi = lane >> 4, llo = lane & 15;
    stage_h(h2all + (size_t)t * NB * NH, smem, tid);
    __syncthreads();

    f32x4 acc[2][2];
#pragma unroll
    for (int nt = 0; nt < 2; ++nt) {
        int col = wave * 32 + nt * 16 + llo;
        float bb = bout[col];
#pragma unroll
        for (int r = 0; r < 4; ++r) { acc[0][nt][r] = bb; acc[1][nt][r] = bb; }
    }
#pragma unroll 8
    for (int kt = 0; kt < 32; ++kt) {
        int kk = kt * 32 + lhi * 8;
        f16x8 a0 = afrag(smem, llo, kk);
        f16x8 a1 = afrag(smem, 16 + llo, kk);
#pragma unroll
        for (int nt = 0; nt < 2; ++nt) {
            int col = wave * 32 + nt * 16 + llo;
            f16x8 bf = *(const f16x8*)(Wout + (size_t)col * NH + kk);
            acc[0][nt] = MFMA16(a0, bf, acc[0][nt]);
            acc[1][nt] = MFMA16(a1, bf, acc[1][nt]);
        }
    }
#pragma unroll
    for (int nt = 0; nt < 2; ++nt) {
        int col = wave * 32 + nt * 16 + llo;
#pragma unroll
        for (int r = 0; r < 4; ++r) {
            out[(size_t)(lhi * 4 + r) * NT * NO + (size_t)t * NO + col] = acc[0][nt][r];
            out[(size_t)(16 + lhi * 4 + r) * NT * NO + (size_t)t * NO + col] = acc[1][nt][r];
        }
    }
}

extern "C" void kernel_launch(void* const* d_in, const int* in_sizes, int n_in,
                              void* d_out, int out_size, void* d_ws, size_t ws_size,
                              hipStream_t stream)
{
    const float* state = (const float*)d_in[0];
    const float* Wih0f = (const float*)d_in[1];
    const float* Whh0f = (const float*)d_in[2];
    const float* b0    = (const float*)d_in[3];
    const float* Wih1f = (const float*)d_in[4];
    const float* Whh1f = (const float*)d_in[5];
    const float* b1    = (const float*)d_in[6];
    const float* Woutf = (const float*)d_in[7];
    const float* bout  = (const float*)d_in[8];
    float* out = (float*)d_out;
    (void)in_sizes; (void)n_in; (void)out_size; (void)ws_size;

    size_t off = 0;
    char* base = (char*)d_ws;
    auto alloc = [&](size_t bytes) -> void* {
        void* p = base + off;
        off += (bytes + 255) & ~(size_t)255;
        return p;
    };
    f16* state16 = (f16*)alloc((size_t)NB * NT * NI * 2);
    f16* Wout    = (f16*)alloc((size_t)NO * NH * 2);
    f16* h1all   = (f16*)alloc((size_t)NT * NB * NH * 2);
    f16* h2all   = (f16*)alloc((size_t)NT * NB * NH * 2);

    convf16<<<(NB * NT * NI + 255) / 256, 256, 0, stream>>>(state, state16, NB * NT * NI);
    convf16<<<(NO * NH + 255) / 256, 256, 0, stream>>>(Woutf, Wout, NO * NH);
    // sentinel-fill h1all+h2all (contiguous) — consumers bypass L2 (SC01)
    hipMemsetAsync(h1all, 0x7F, (size_t)2 * NT * NB * NH * 2, stream);

    hipFuncSetAttribute((const void*)persist,
                        hipFuncAttributeMaxDynamicSharedMemorySize, 86016);
    persist<<<256, 256, 86016, stream>>>(Wih0f, Whh0f, b0, Wih1f, Whh1f, b1,
                                         state16, h1all, h2all);
    head_kernel<<<NT, 256, 0, stream>>>(h2all, Wout, bout, out);
}

// Round 14
// 2814.293 us; speedup vs baseline: 1.2603x; 1.0137x over previous
//
#include <hip/hip_runtime.h>

#define NB 32
#define NT 512
#define NI 128
#define NH 1024
#define NG 4096
#define NO 128

typedef _Float16 f16;
typedef _Float16 f16x8 __attribute__((ext_vector_type(8)));
typedef float f32x4 __attribute__((ext_vector_type(4)));
typedef int int4v __attribute__((ext_vector_type(4)));
typedef unsigned long long ull;

#define MFMA16(a, b, c) __builtin_amdgcn_mfma_f32_16x16x32_f16(a, b, c, 0, 0, 0)
#define SENTD 0x7F7F7F7Fu

__device__ __forceinline__ float sigm(float x) { return 1.f / (1.f + __expf(-x)); }
__device__ __forceinline__ float tanh_(float x) {
    float a = fabsf(x);
    float e = __expf(-2.f * a);
    float r = (1.f - e) / (1.f + e);
    return x < 0.f ? -r : r;
}
// valid when NO dword equals the 0x7F7F7F7F sentinel (f16 NaN pair; |h|<1
// so real packed h never encodes as it)
__device__ __forceinline__ bool ok16(int4v v) {
    return v.x != (int)SENTD && v.y != (int)SENTD && v.z != (int)SENTD && v.w != (int)SENTD;
}
__device__ __forceinline__ void astore64(void* p, ull v) {
    __hip_atomic_store((ull*)p, v, __ATOMIC_RELAXED, __HIP_MEMORY_SCOPE_AGENT);
}
__device__ __forceinline__ f16x8 ld8f(const float* s) {
    float4 x0 = *(const float4*)s, x1 = *(const float4*)(s + 4);
    f16x8 v;
    v[0] = (f16)x0.x; v[1] = (f16)x0.y; v[2] = (f16)x0.z; v[3] = (f16)x0.w;
    v[4] = (f16)x1.x; v[5] = (f16)x1.y; v[6] = (f16)x1.z; v[7] = (f16)x1.w;
    return v;
}
// 16B load, L1+L2-bypass (L3-direct): always coherent with agent-atomic
// stores from any XCD; no fences, no stale-line hazard.
#define LOAD_SC01(dst, addr) \
    asm volatile("global_load_dwordx4 %0, %1, off sc0 sc1" : "=v"(dst) : "v"(addr))
#define WAITV0() do { asm volatile("s_waitcnt vmcnt(0)" ::: "memory"); \
                      __builtin_amdgcn_sched_barrier(0); } while (0)
// wait until at most 8 VMEM ops outstanding (retires the older v1 batch)
#define WAITV8() do { asm volatile("s_waitcnt vmcnt(8)" ::: "memory"); \
                      __builtin_amdgcn_sched_barrier(0); } while (0)

__global__ void convf16(const float* __restrict__ src, f16* __restrict__ dst, int n) {
    int i = blockIdx.x * blockDim.x + threadIdx.x;
    if (i < n) dst[i] = (f16)src[i];
}

// ---------------------------------------------------------------------------
// Persistent pipeline (R13 + double-buffered gbuf -> single barrier/step):
// 256 WGs x 256 thr, 1 WG/CU (forced by 84KB dyn LDS).
//  bid [0,128)   R1: layer-1 step, (16 batch, 16 units)/CU, K=1152 (state|h1).
//  bid [128,256) R2: layer-2 step + input proj, (16 batch, 16 units)/CU,
//                two K=1024 matmuls (h1[t]@Wih1 + h2[t-1]@Whh1).
// Weights in VGPRs (K split across 4 waves, 4 gates). A-fragments go straight
// from global loads into MFMA. Producers publish packed 8B agent-scope
// atomic stores (L3-resident). Consumers bulk-read h with SC01 16B loads
// (L3-direct, always fresh); any fragment still sentinel is re-read with the
// same SC01 loads. R2 waits vmcnt(8) to validate v1 early and runs its 32
// v1-MFMAs while the critical h2[t-1] loads are in flight. gbuf is double-
// buffered by t&1, so only ONE __syncthreads per step (WAR on gbuf is
// ordered through the next step's barrier). No flags, no fences, no rings
// -> deadlock-impossible.
// ---------------------------------------------------------------------------
extern "C" __global__ __launch_bounds__(256, 1) void persist(
    const float* __restrict__ Wih0f, const float* __restrict__ Whh0f, const float* __restrict__ b0,
    const float* __restrict__ Wih1f, const float* __restrict__ Whh1f, const float* __restrict__ b1,
    const f16* __restrict__ state16,
    f16* __restrict__ h1all,      // [NT][NB][NH], 0x7F-filled
    f16* __restrict__ h2all)      // [NT][NB][NH], 0x7F-filled
{
    extern __shared__ char smem[];
    float* gbuf = (float*)smem;   // 2 x [16][16*17] f32 partials (+17 pad)
    const int bid = blockIdx.x;
    const int tid = threadIdx.x;
    const int w = tid >> 6;
    const int lane = tid & 63;
    const int llo = lane & 15;
    const int lhi = lane >> 4;
    const int rb = tid >> 2;        // elementwise: batch row (threads 0..63)
    const int uq = (tid & 3) * 4;   // elementwise: unit quad base

    if (bid < 128) {
        // ============================ R1 ============================
        const int bs = bid >> 6, us = bid & 63;
        const int bbase = bs * 16, ubase = us * 16;
        // weights: wave w owns ks = w*9+i (K=1152), 4 gate-column blocks
        f16x8 wr[36];
#pragma unroll
        for (int g = 0; g < 4; ++g)
#pragma unroll
            for (int i = 0; i < 9; ++i) {
                int kpos = (w * 9 + i) * 32 + lhi * 8;
                int col = g * NH + ubase + llo;
                const float* s = (kpos < 128) ? (Wih0f + (size_t)col * NI + kpos)
                                              : (Whh0f + (size_t)col * NH + (kpos - 128));
                wr[g * 9 + i] = ld8f(s);
            }
        float cc[4] = {0.f, 0.f, 0.f, 0.f};
        float Bi[4], Bff[4], Bg[4], Bo[4];
        if (tid < 64) {
#pragma unroll
            for (int u = 0; u < 4; ++u) {
                Bi[u]  = b0[0 * NH + ubase + uq + u];
                Bff[u] = b0[1 * NH + ubase + uq + u];
                Bg[u]  = b0[2 * NH + ubase + uq + u];
                Bo[u]  = b0[3 * NH + ubase + uq + u];
            }
        }

        for (int t = 0; t < NT; ++t) {
            float* gb = gbuf + (t & 1) * 4352;
            const f16* hprev = h1all + (size_t)(t - 1) * NB * NH;
            const int row = bbase + llo;
            // ---- bulk SC01 loads (L3-direct), sentinel-validate, SC01 retry ----
            int4v vv[9];
#pragma unroll
            for (int i = 0; i < 9; ++i) {
                int kpos = (w * 9 + i) * 32 + lhi * 8;
                if (kpos < 128)
                    vv[i] = *(const int4v*)(state16 + ((size_t)row * NT + t) * NI + kpos);
                else if (t > 0) {
                    LOAD_SC01(vv[i], hprev + (size_t)row * NH + (kpos - 128));
                } else
                    vv[i] = int4v{};
            }
            if (t > 0) {
                WAITV0();
                unsigned pend = 0;
#pragma unroll
                for (int i = 0; i < 9; ++i) {
                    int kpos = (w * 9 + i) * 32 + lhi * 8;
                    if (kpos >= 128 && !ok16(vv[i])) pend |= 1u << i;
                }
                while (__builtin_expect(pend != 0, 0)) {
#pragma unroll
                    for (int i = 0; i < 9; ++i)
                        if (pend & (1u << i)) {
                            int kpos = (w * 9 + i) * 32 + lhi * 8;
                            LOAD_SC01(vv[i], hprev + (size_t)row * NH + (kpos - 128));
                        }
                    WAITV0();
#pragma unroll
                    for (int i = 0; i < 9; ++i)
                        if ((pend & (1u << i)) && ok16(vv[i])) pend &= ~(1u << i);
                    if (pend) __builtin_amdgcn_s_sleep(1);
                }
            }
            // ---- MFMA directly on loaded fragments (K-split partials) ----
            f32x4 acc[4] = {};
#pragma unroll
            for (int i = 0; i < 9; ++i) {
                f16x8 av = __builtin_bit_cast(f16x8, vv[i]);
#pragma unroll
                for (int g = 0; g < 4; ++g)
                    acc[g] = MFMA16(av, wr[g * 9 + i], acc[g]);
            }
            // dbuf: writes go to gb(t); prev step's readers used gb(t-1)
#pragma unroll
            for (int g = 0; g < 4; ++g)
#pragma unroll
                for (int r = 0; r < 4; ++r)
                    gb[(w * 4 + g) * 272 + (lhi * 4 + r) * 17 + llo] = acc[g][r];
            __syncthreads();   // single barrier: partials ready
            // ---- reduce + elementwise + packed publish (threads 0..63) ----
            if (tid < 64) {
                ull pack = 0;
#pragma unroll
                for (int u = 0; u < 4; ++u) {
                    int un = uq + u;
                    float s0 = 0, s1 = 0, s2 = 0, s3 = 0;
#pragma unroll
                    for (int w2 = 0; w2 < 4; ++w2) {
                        s0 += gb[(w2 * 4 + 0) * 272 + rb * 17 + un];
                        s1 += gb[(w2 * 4 + 1) * 272 + rb * 17 + un];
                        s2 += gb[(w2 * 4 + 2) * 272 + rb * 17 + un];
                        s3 += gb[(w2 * 4 + 3) * 272 + rb * 17 + un];
                    }
                    float i_ = sigm(s0 + Bi[u]), f_ = sigm(s1 + Bff[u]);
                    float g_ = tanh_(s2 + Bg[u]), o_ = sigm(s3 + Bo[u]);
                    cc[u] = f_ * cc[u] + i_ * g_;
                    float h = o_ * tanh_(cc[u]);
                    unsigned short hb = __builtin_bit_cast(unsigned short, (f16)h);
                    pack |= (ull)hb << (16 * u);
                }
                astore64(h1all + ((size_t)t * NB + bbase + rb) * NH + ubase + uq, pack);
            }
        }
    } else {
        // ====================== R2 (merged P) ======================
        const int b2 = bid - 128, bs = b2 >> 6, us = b2 & 63;
        const int bbase = bs * 16, ubase = us * 16;
        f16x8 wr1[32], wr2[32];   // Wih1, Whh1: wave w owns ks = w*8+i
#pragma unroll
        for (int g = 0; g < 4; ++g)
#pragma unroll
            for (int i = 0; i < 8; ++i) {
                int kpos = (w * 8 + i) * 32 + lhi * 8;
                int col = g * NH + ubase + llo;
                wr1[g * 8 + i] = ld8f(Wih1f + (size_t)col * NH + kpos);
                wr2[g * 8 + i] = ld8f(Whh1f + (size_t)col * NH + kpos);
            }
        float cc[4] = {0.f, 0.f, 0.f, 0.f};
        float Bi[4], Bff[4], Bg[4], Bo[4];
        if (tid < 64) {
#pragma unroll
            for (int u = 0; u < 4; ++u) {
                Bi[u]  = b1[0 * NH + ubase + uq + u];
                Bff[u] = b1[1 * NH + ubase + uq + u];
                Bg[u]  = b1[2 * NH + ubase + uq + u];
                Bo[u]  = b1[3 * NH + ubase + uq + u];
            }
        }
        const int row = bbase + llo;

        for (int t = 0; t < NT; ++t) {
            float* gb = gbuf + (t & 1) * 4352;
            const f16* A1 = h1all + (size_t)t * NB * NH;
            const f16* A2 = h2all + (size_t)(t - 1) * NB * NH;
            int4v v1[8], v2[8];
            // issue v1 (usually ready: R1 runs ahead), then v2 (critical spin)
#pragma unroll
            for (int i = 0; i < 8; ++i) {
                int kpos = (w * 8 + i) * 32 + lhi * 8;
                LOAD_SC01(v1[i], A1 + (size_t)row * NH + kpos);
            }
            if (t > 0) {
#pragma unroll
                for (int i = 0; i < 8; ++i) {
                    int kpos = (w * 8 + i) * 32 + lhi * 8;
                    LOAD_SC01(v2[i], A2 + (size_t)row * NH + kpos);
                }
                WAITV8();   // retire v1 batch only; v2 still in flight
            } else {
#pragma unroll
                for (int i = 0; i < 8; ++i) v2[i] = int4v{};
                WAITV0();
            }
            // ---- validate v1 (retry rare), then run v1 MFMAs under v2 flight ----
            unsigned p1 = 0;
#pragma unroll
            for (int i = 0; i < 8; ++i)
                if (!ok16(v1[i])) p1 |= 1u << i;
            while (__builtin_expect(p1 != 0, 0)) {
#pragma unroll
                for (int i = 0; i < 8; ++i)
                    if (p1 & (1u << i)) {
                        int kpos = (w * 8 + i) * 32 + lhi * 8;
                        LOAD_SC01(v1[i], A1 + (size_t)row * NH + kpos);
                    }
                WAITV0();
#pragma unroll
                for (int i = 0; i < 8; ++i)
                    if ((p1 & (1u << i)) && ok16(v1[i])) p1 &= ~(1u << i);
                if (p1) __builtin_amdgcn_s_sleep(1);
            }
            f32x4 acc[4] = {};
#pragma unroll
            for (int i = 0; i < 8; ++i) {
                f16x8 a1 = __builtin_bit_cast(f16x8, v1[i]);
#pragma unroll
                for (int g = 0; g < 4; ++g)
                    acc[g] = MFMA16(a1, wr1[g * 8 + i], acc[g]);
            }
            // ---- now the critical v2 (h2[t-1]) spin + MFMAs ----
            WAITV0();
            unsigned p2 = 0;
            if (t > 0) {
#pragma unroll
                for (int i = 0; i < 8; ++i)
                    if (!ok16(v2[i])) p2 |= 1u << i;
            }
            while (__builtin_expect(p2 != 0, 0)) {
#pragma unroll
                for (int i = 0; i < 8; ++i)
                    if (p2 & (1u << i)) {
                        int kpos = (w * 8 + i) * 32 + lhi * 8;
                        LOAD_SC01(v2[i], A2 + (size_t)row * NH + kpos);
                    }
                WAITV0();
#pragma unroll
                for (int i = 0; i < 8; ++i)
                    if ((p2 & (1u << i)) && ok16(v2[i])) p2 &= ~(1u << i);
                if (p2) __builtin_amdgcn_s_sleep(1);
            }
#pragma unroll
            for (int i = 0; i < 8; ++i) {
                f16x8 a2 = __builtin_bit_cast(f16x8, v2[i]);
#pragma unroll
                for (int g = 0; g < 4; ++g)
                    acc[g] = MFMA16(a2, wr2[g * 8 + i], acc[g]);
            }
            // dbuf write; single barrier
#pragma unroll
            for (int g = 0; g < 4; ++g)
#pragma unroll
                for (int r = 0; r < 4; ++r)
                    gb[(w * 4 + g) * 272 + (lhi * 4 + r) * 17 + llo] = acc[g][r];
            __syncthreads();
            if (tid < 64) {
                ull pack = 0;
#pragma unroll
                for (int u = 0; u < 4; ++u) {
                    int un = uq + u;
                    float s0 = 0, s1 = 0, s2 = 0, s3 = 0;
#pragma unroll
                    for (int w2 = 0; w2 < 4; ++w2) {
                        s0 += gb[(w2 * 4 + 0) * 272 + rb * 17 + un];
                        s1 += gb[(w2 * 4 + 1) * 272 + rb * 17 + un];
                        s2 += gb[(w2 * 4 + 2) * 272 + rb * 17 + un];
                        s3 += gb[(w2 * 4 + 3) * 272 + rb * 17 + un];
                    }
                    float i_ = sigm(s0 + Bi[u]), f_ = sigm(s1 + Bff[u]);
                    float g_ = tanh_(s2 + Bg[u]), o_ = sigm(s3 + Bo[u]);
                    cc[u] = f_ * cc[u] + i_ * g_;
                    float h = o_ * tanh_(cc[u]);
                    unsigned short hb = __builtin_bit_cast(unsigned short, (f16)h);
                    pack |= (ull)hb << (16 * u);
                }
                astore64(h2all + ((size_t)t * NB + bbase + rb) * NH + ubase + uq, pack);
            }
        }
    }
}

// ---------------------------------------------------------------------------
// Head: out[b][t][o] = h2[b][t][:] @ W_out^T + b_out ; one WG per t
// ---------------------------------------------------------------------------
__device__ __forceinline__ void stage_h(const f16* __restrict__ hsrc, char* smem, int tid) {
    const float4* src = (const float4*)hsrc;
#pragma unroll
    for (int i = 0; i < 16; ++i) {
        int c = i * 256 + tid;
        int off = c * 16;
        int swz = off ^ (((off >> 11) & 7) << 4);
        *(float4*)(smem + swz) = src[c];
    }
}
__device__ __forceinline__ f16x8 afrag(const char* smem, int row, int kk) {
    int off = (row << 11) + kk * 2;
    off ^= ((row & 7) << 4);
    return *(const f16x8*)(smem + off);
}

__global__ __launch_bounds__(256) void head_kernel(
    const f16* __restrict__ h2all, const f16* __restrict__ Wout,
    const float* __restrict__ bout, float* __restrict__ out)
{
    __shared__ __align__(16) char smem[65536];
    int t = blockIdx.x;
    int tid = threadIdx.x;
    int wave = tid >> 6, lane = tid & 63, lhi = lane >> 4, llo = lane & 15;
    stage_h(h2all + (size_t)t * NB * NH, smem, tid);
    __syncthreads();

    f32x4 acc[2][2];
#pragma unroll
    for (int nt = 0; nt < 2; ++nt) {
        int col = wave * 32 + nt * 16 + llo;
        float bb = bout[col];
#pragma unroll
        for (int r = 0; r < 4; ++r) { acc[0][nt][r] = bb; acc[1][nt][r] = bb; }
    }
#pragma unroll 8
    for (int kt = 0; kt < 32; ++kt) {
        int kk = kt * 32 + lhi * 8;
        f16x8 a0 = afrag(smem, llo, kk);
        f16x8 a1 = afrag(smem, 16 + llo, kk);
#pragma unroll
        for (int nt = 0; nt < 2; ++nt) {
            int col = wave * 32 + nt * 16 + llo;
            f16x8 bf = *(const f16x8*)(Wout + (size_t)col * NH + kk);
            acc[0][nt] = MFMA16(a0, bf, acc[0][nt]);
            acc[1][nt] = MFMA16(a1, bf, acc[1][nt]);
        }
    }
#pragma unroll
    for (int nt = 0; nt < 2; ++nt) {
        int col = wave * 32 + nt * 16 + llo;
#pragma unroll
        for (int r = 0; r < 4; ++r) {
            out[(size_t)(lhi * 4 + r) * NT * NO + (size_t)t * NO + col] = acc[0][nt][r];
            out[(size_t)(16 + lhi * 4 + r) * NT * NO + (size_t)t * NO + col] = acc[1][nt][r];
        }
    }
}

extern "C" void kernel_launch(void* const* d_in, const int* in_sizes, int n_in,
                              void* d_out, int out_size, void* d_ws, size_t ws_size,
                              hipStream_t stream)
{
    const float* state = (const float*)d_in[0];
    const float* Wih0f = (const float*)d_in[1];
    const float* Whh0f = (const float*)d_in[2];
    const float* b0    = (const float*)d_in[3];
    const float* Wih1f = (const float*)d_in[4];
    const float* Whh1f = (const float*)d_in[5];
    const float* b1    = (const float*)d_in[6];
    const float* Woutf = (const float*)d_in[7];
    const float* bout  = (const float*)d_in[8];
    float* out = (float*)d_out;
    (void)in_sizes; (void)n_in; (void)out_size; (void)ws_size;

    size_t off = 0;
    char* base = (char*)d_ws;
    auto alloc = [&](size_t bytes) -> void* {
        void* p = base + off;
        off += (bytes + 255) & ~(size_t)255;
        return p;
    };
    f16* state16 = (f16*)alloc((size_t)NB * NT * NI * 2);
    f16* Wout    = (f16*)alloc((size_t)NO * NH * 2);
    f16* h1all   = (f16*)alloc((size_t)NT * NB * NH * 2);
    f16* h2all   = (f16*)alloc((size_t)NT * NB * NH * 2);

    convf16<<<(NB * NT * NI + 255) / 256, 256, 0, stream>>>(state, state16, NB * NT * NI);
    convf16<<<(NO * NH + 255) / 256, 256, 0, stream>>>(Woutf, Wout, NO * NH);
    // sentinel-fill h1all+h2all (contiguous) — consumers bypass L2 (SC01)
    hipMemsetAsync(h1all, 0x7F, (size_t)2 * NT * NB * NH * 2, stream);

    hipFuncSetAttribute((const void*)persist,
                        hipFuncAttributeMaxDynamicSharedMemorySize, 86016);
    persist<<<256, 256, 86016, stream>>>(Wih0f, Whh0f, b0, Wih1f, Whh1f, b1,
                                         state16, h1all, h2all);
    head_kernel<<<NT, 256, 0, stream>>>(h2all, Wout, bout, out);
}

// Round 17
// 2813.587 us; speedup vs baseline: 1.2606x; 1.0003x over previous
//
#include <hip/hip_runtime.h>

#define NB 32
#define NT 512
#define NI 128
#define NH 1024
#define NG 4096
#define NO 128

typedef _Float16 f16;
typedef _Float16 f16x8 __attribute__((ext_vector_type(8)));
typedef float f32x4 __attribute__((ext_vector_type(4)));
typedef int int4v __attribute__((ext_vector_type(4)));
typedef unsigned long long ull;

#define MFMA16(a, b, c) __builtin_amdgcn_mfma_f32_16x16x32_f16(a, b, c, 0, 0, 0)
#define SENTD 0x7F7F7F7Fu

__device__ __forceinline__ float sigm(float x) { return 1.f / (1.f + __expf(-x)); }
__device__ __forceinline__ float tanh_(float x) {
    float a = fabsf(x);
    float e = __expf(-2.f * a);
    float r = (1.f - e) / (1.f + e);
    return x < 0.f ? -r : r;
}
// valid when NO dword equals the 0x7F7F7F7F sentinel (f16 NaN pair; |h|<1
// so real packed h never encodes as it)
__device__ __forceinline__ bool ok16(int4v v) {
    return v.x != (int)SENTD && v.y != (int)SENTD && v.z != (int)SENTD && v.w != (int)SENTD;
}
__device__ __forceinline__ void astore64(void* p, ull v) {
    __hip_atomic_store((ull*)p, v, __ATOMIC_RELAXED, __HIP_MEMORY_SCOPE_AGENT);
}
__device__ __forceinline__ f16x8 ld8f(const float* s) {
    float4 x0 = *(const float4*)s, x1 = *(const float4*)(s + 4);
    f16x8 v;
    v[0] = (f16)x0.x; v[1] = (f16)x0.y; v[2] = (f16)x0.z; v[3] = (f16)x0.w;
    v[4] = (f16)x1.x; v[5] = (f16)x1.y; v[6] = (f16)x1.z; v[7] = (f16)x1.w;
    return v;
}
// 16B load, L1+L2-bypass (L3-direct): always coherent with agent-atomic
// stores from any XCD; no fences, no stale-line hazard.
#define LOAD_SC01(dst, addr) \
    asm volatile("global_load_dwordx4 %0, %1, off sc0 sc1" : "=v"(dst) : "v"(addr))
#define WAITV0() do { asm volatile("s_waitcnt vmcnt(0)" ::: "memory"); \
                      __builtin_amdgcn_sched_barrier(0); } while (0)
// wait until at most 8 VMEM ops outstanding (retires the older v1 batch)
#define WAITV8() do { asm volatile("s_waitcnt vmcnt(8)" ::: "memory"); \
                      __builtin_amdgcn_sched_barrier(0); } while (0)

__global__ void convf16(const float* __restrict__ src, f16* __restrict__ dst, int n) {
    int i = blockIdx.x * blockDim.x + threadIdx.x;
    if (i < n) dst[i] = (f16)src[i];
}

// ---------------------------------------------------------------------------
// Persistent pipeline (R13 + double-buffered gbuf -> single barrier/step):
// 256 WGs x 256 thr, 1 WG/CU (forced by 84KB dyn LDS).
//  bid [0,128)   R1: layer-1 step, (16 batch, 16 units)/CU, K=1152 (state|h1).
//  bid [128,256) R2: layer-2 step + input proj, (16 batch, 16 units)/CU,
//                two K=1024 matmuls (h1[t]@Wih1 + h2[t-1]@Whh1).
// Weights in VGPRs (K split across 4 waves, 4 gates). A-fragments go straight
// from global loads into MFMA. Producers publish packed 8B agent-scope
// atomic stores (L3-resident). Consumers bulk-read h with SC01 16B loads
// (L3-direct, always fresh); any fragment still sentinel is re-read with the
// same SC01 loads. R2 waits vmcnt(8) to validate v1 early and runs its 32
// v1-MFMAs while the critical h2[t-1] loads are in flight. gbuf is double-
// buffered by t&1, so only ONE __syncthreads per step (WAR on gbuf is
// ordered through the next step's barrier). No flags, no fences, no rings
// -> deadlock-impossible.
// ---------------------------------------------------------------------------
extern "C" __global__ __launch_bounds__(256, 1) void persist(
    const float* __restrict__ Wih0f, const float* __restrict__ Whh0f, const float* __restrict__ b0,
    const float* __restrict__ Wih1f, const float* __restrict__ Whh1f, const float* __restrict__ b1,
    const f16* __restrict__ state16,
    f16* __restrict__ h1all,      // [NT][NB][NH], 0x7F-filled
    f16* __restrict__ h2all)      // [NT][NB][NH], 0x7F-filled
{
    extern __shared__ char smem[];
    float* gbuf = (float*)smem;   // 2 x [16][16*17] f32 partials (+17 pad)
    const int bid = blockIdx.x;
    const int tid = threadIdx.x;
    const int w = tid >> 6;
    const int lane = tid & 63;
    const int llo = lane & 15;
    const int lhi = lane >> 4;
    const int rb = tid >> 2;        // elementwise: batch row (threads 0..63)
    const int uq = (tid & 3) * 4;   // elementwise: unit quad base

    if (bid < 128) {
        // ============================ R1 ============================
        const int bs = bid >> 6, us = bid & 63;
        const int bbase = bs * 16, ubase = us * 16;
        // weights: wave w owns ks = w*9+i (K=1152), 4 gate-column blocks
        f16x8 wr[36];
#pragma unroll
        for (int g = 0; g < 4; ++g)
#pragma unroll
            for (int i = 0; i < 9; ++i) {
                int kpos = (w * 9 + i) * 32 + lhi * 8;
                int col = g * NH + ubase + llo;
                const float* s = (kpos < 128) ? (Wih0f + (size_t)col * NI + kpos)
                                              : (Whh0f + (size_t)col * NH + (kpos - 128));
                wr[g * 9 + i] = ld8f(s);
            }
        float cc[4] = {0.f, 0.f, 0.f, 0.f};
        float Bi[4], Bff[4], Bg[4], Bo[4];
        if (tid < 64) {
#pragma unroll
            for (int u = 0; u < 4; ++u) {
                Bi[u]  = b0[0 * NH + ubase + uq + u];
                Bff[u] = b0[1 * NH + ubase + uq + u];
                Bg[u]  = b0[2 * NH + ubase + uq + u];
                Bo[u]  = b0[3 * NH + ubase + uq + u];
            }
        }

        for (int t = 0; t < NT; ++t) {
            float* gb = gbuf + (t & 1) * 4352;
            const f16* hprev = h1all + (size_t)(t - 1) * NB * NH;
            const int row = bbase + llo;
            // ---- bulk SC01 loads (L3-direct), sentinel-validate, SC01 retry ----
            int4v vv[9];
#pragma unroll
            for (int i = 0; i < 9; ++i) {
                int kpos = (w * 9 + i) * 32 + lhi * 8;
                if (kpos < 128)
                    vv[i] = *(const int4v*)(state16 + ((size_t)row * NT + t) * NI + kpos);
                else if (t > 0) {
                    LOAD_SC01(vv[i], hprev + (size_t)row * NH + (kpos - 128));
                } else
                    vv[i] = int4v{};
            }
            if (t > 0) {
                WAITV0();
                unsigned pend = 0;
#pragma unroll
                for (int i = 0; i < 9; ++i) {
                    int kpos = (w * 9 + i) * 32 + lhi * 8;
                    if (kpos >= 128 && !ok16(vv[i])) pend |= 1u << i;
                }
                while (__builtin_expect(pend != 0, 0)) {
#pragma unroll
                    for (int i = 0; i < 9; ++i)
                        if (pend & (1u << i)) {
                            int kpos = (w * 9 + i) * 32 + lhi * 8;
                            LOAD_SC01(vv[i], hprev + (size_t)row * NH + (kpos - 128));
                        }
                    WAITV0();
#pragma unroll
                    for (int i = 0; i < 9; ++i)
                        if ((pend & (1u << i)) && ok16(vv[i])) pend &= ~(1u << i);
                    if (pend) __builtin_amdgcn_s_sleep(1);
                }
            }
            // ---- MFMA directly on loaded fragments (K-split partials) ----
            f32x4 acc[4] = {};
#pragma unroll
            for (int i = 0; i < 9; ++i) {
                f16x8 av = __builtin_bit_cast(f16x8, vv[i]);
#pragma unroll
                for (int g = 0; g < 4; ++g)
                    acc[g] = MFMA16(av, wr[g * 9 + i], acc[g]);
            }
            // dbuf: writes go to gb(t); prev step's readers used gb(t-1)
#pragma unroll
            for (int g = 0; g < 4; ++g)
#pragma unroll
                for (int r = 0; r < 4; ++r)
                    gb[(w * 4 + g) * 272 + (lhi * 4 + r) * 17 + llo] = acc[g][r];
            __syncthreads();   // single barrier: partials ready
            // ---- reduce + elementwise + packed publish (threads 0..63) ----
            if (tid < 64) {
                ull pack = 0;
#pragma unroll
                for (int u = 0; u < 4; ++u) {
                    int un = uq + u;
                    float s0 = 0, s1 = 0, s2 = 0, s3 = 0;
#pragma unroll
                    for (int w2 = 0; w2 < 4; ++w2) {
                        s0 += gb[(w2 * 4 + 0) * 272 + rb * 17 + un];
                        s1 += gb[(w2 * 4 + 1) * 272 + rb * 17 + un];
                        s2 += gb[(w2 * 4 + 2) * 272 + rb * 17 + un];
                        s3 += gb[(w2 * 4 + 3) * 272 + rb * 17 + un];
                    }
                    float i_ = sigm(s0 + Bi[u]), f_ = sigm(s1 + Bff[u]);
                    float g_ = tanh_(s2 + Bg[u]), o_ = sigm(s3 + Bo[u]);
                    cc[u] = f_ * cc[u] + i_ * g_;
                    float h = o_ * tanh_(cc[u]);
                    unsigned short hb = __builtin_bit_cast(unsigned short, (f16)h);
                    pack |= (ull)hb << (16 * u);
                }
                astore64(h1all + ((size_t)t * NB + bbase + rb) * NH + ubase + uq, pack);
            }
        }
    } else {
        // ====================== R2 (merged P) ======================
        const int b2 = bid - 128, bs = b2 >> 6, us = b2 & 63;
        const int bbase = bs * 16, ubase = us * 16;
        f16x8 wr1[32], wr2[32];   // Wih1, Whh1: wave w owns ks = w*8+i
#pragma unroll
        for (int g = 0; g < 4; ++g)
#pragma unroll
            for (int i = 0; i < 8; ++i) {
                int kpos = (w * 8 + i) * 32 + lhi * 8;
                int col = g * NH + ubase + llo;
                wr1[g * 8 + i] = ld8f(Wih1f + (size_t)col * NH + kpos);
                wr2[g * 8 + i] = ld8f(Whh1f + (size_t)col * NH + kpos);
            }
        float cc[4] = {0.f, 0.f, 0.f, 0.f};
        float Bi[4], Bff[4], Bg[4], Bo[4];
        if (tid < 64) {
#pragma unroll
            for (int u = 0; u < 4; ++u) {
                Bi[u]  = b1[0 * NH + ubase + uq + u];
                Bff[u] = b1[1 * NH + ubase + uq + u];
                Bg[u]  = b1[2 * NH + ubase + uq + u];
                Bo[u]  = b1[3 * NH + ubase + uq + u];
            }
        }
        const int row = bbase + llo;

        for (int t = 0; t < NT; ++t) {
            float* gb = gbuf + (t & 1) * 4352;
            const f16* A1 = h1all + (size_t)t * NB * NH;
            const f16* A2 = h2all + (size_t)(t - 1) * NB * NH;
            int4v v1[8], v2[8];
            // issue v1 (usually ready: R1 runs ahead), then v2 (critical spin)
#pragma unroll
            for (int i = 0; i < 8; ++i) {
                int kpos = (w * 8 + i) * 32 + lhi * 8;
                LOAD_SC01(v1[i], A1 + (size_t)row * NH + kpos);
            }
            if (t > 0) {
#pragma unroll
                for (int i = 0; i < 8; ++i) {
                    int kpos = (w * 8 + i) * 32 + lhi * 8;
                    LOAD_SC01(v2[i], A2 + (size_t)row * NH + kpos);
                }
                WAITV8();   // retire v1 batch only; v2 still in flight
            } else {
#pragma unroll
                for (int i = 0; i < 8; ++i) v2[i] = int4v{};
                WAITV0();
            }
            // ---- validate v1 (retry rare), then run v1 MFMAs under v2 flight ----
            unsigned p1 = 0;
#pragma unroll
            for (int i = 0; i < 8; ++i)
                if (!ok16(v1[i])) p1 |= 1u << i;
            while (__builtin_expect(p1 != 0, 0)) {
#pragma unroll
                for (int i = 0; i < 8; ++i)
                    if (p1 & (1u << i)) {
                        int kpos = (w * 8 + i) * 32 + lhi * 8;
                        LOAD_SC01(v1[i], A1 + (size_t)row * NH + kpos);
                    }
                WAITV0();
#pragma unroll
                for (int i = 0; i < 8; ++i)
                    if ((p1 & (1u << i)) && ok16(v1[i])) p1 &= ~(1u << i);
                if (p1) __builtin_amdgcn_s_sleep(1);
            }
            f32x4 acc[4] = {};
#pragma unroll
            for (int i = 0; i < 8; ++i) {
                f16x8 a1 = __builtin_bit_cast(f16x8, v1[i]);
#pragma unroll
                for (int g = 0; g < 4; ++g)
                    acc[g] = MFMA16(a1, wr1[g * 8 + i], acc[g]);
            }
            // ---- now the critical v2 (h2[t-1]) spin + MFMAs ----
            WAITV0();
            unsigned p2 = 0;
            if (t > 0) {
#pragma unroll
                for (int i = 0; i < 8; ++i)
                    if (!ok16(v2[i])) p2 |= 1u << i;
            }
            while (__builtin_expect(p2 != 0, 0)) {
#pragma unroll
                for (int i = 0; i < 8; ++i)
                    if (p2 & (1u << i)) {
                        int kpos = (w * 8 + i) * 32 + lhi * 8;
                        LOAD_SC01(v2[i], A2 + (size_t)row * NH + kpos);
                    }
                WAITV0();
#pragma unroll
                for (int i = 0; i < 8; ++i)
                    if ((p2 & (1u << i)) && ok16(v2[i])) p2 &= ~(1u << i);
                if (p2) __builtin_amdgcn_s_sleep(1);
            }
#pragma unroll
            for (int i = 0; i < 8; ++i) {
                f16x8 a2 = __builtin_bit_cast(f16x8, v2[i]);
#pragma unroll
                for (int g = 0; g < 4; ++g)
                    acc[g] = MFMA16(a2, wr2[g * 8 + i], acc[g]);
            }
            // dbuf write; single barrier
#pragma unroll
            for (int g = 0; g < 4; ++g)
#pragma unroll
                for (int r = 0; r < 4; ++r)
                    gb[(w * 4 + g) * 272 + (lhi * 4 + r) * 17 + llo] = acc[g][r];
            __syncthreads();
            if (tid < 64) {
                ull pack = 0;
#pragma unroll
                for (int u = 0; u < 4; ++u) {
                    int un = uq + u;
                    float s0 = 0, s1 = 0, s2 = 0, s3 = 0;
#pragma unroll
                    for (int w2 = 0; w2 < 4; ++w2) {
                        s0 += gb[(w2 * 4 + 0) * 272 + rb * 17 + un];
                        s1 += gb[(w2 * 4 + 1) * 272 + rb * 17 + un];
                        s2 += gb[(w2 * 4 + 2) * 272 + rb * 17 + un];
                        s3 += gb[(w2 * 4 + 3) * 272 + rb * 17 + un];
                    }
                    float i_ = sigm(s0 + Bi[u]), f_ = sigm(s1 + Bff[u]);
                    float g_ = tanh_(s2 + Bg[u]), o_ = sigm(s3 + Bo[u]);
                    cc[u] = f_ * cc[u] + i_ * g_;
                    float h = o_ * tanh_(cc[u]);
                    unsigned short hb = __builtin_bit_cast(unsigned short, (f16)h);
                    pack |= (ull)hb << (16 * u);
                }
                astore64(h2all + ((size_t)t * NB + bbase + rb) * NH + ubase + uq, pack);
            }
        }
    }
}

// ---------------------------------------------------------------------------
// Head: out[b][t][o] = h2[b][t][:] @ W_out^T + b_out ; one WG per t
// ---------------------------------------------------------------------------
__device__ __forceinline__ void stage_h(const f16* __restrict__ hsrc, char* smem, int tid) {
    const float4* src = (const float4*)hsrc;
#pragma unroll
    for (int i = 0; i < 16; ++i) {
        int c = i * 256 + tid;
        int off = c * 16;
        int swz = off ^ (((off >> 11) & 7) << 4);
        *(float4*)(smem + swz) = src[c];
    }
}
__device__ __forceinline__ f16x8 afrag(const char* smem, int row, int kk) {
    int off = (row << 11) + kk * 2;
    off ^= ((row & 7) << 4);
    return *(const f16x8*)(smem + off);
}

__global__ __launch_bounds__(256) void head_kernel(
    const f16* __restrict__ h2all, const f16* __restrict__ Wout,
    const float* __restrict__ bout, float* __restrict__ out)
{
    __shared__ __align__(16) char smem[65536];
    int t = blockIdx.x;
    int tid = threadIdx.x;
    int wave = tid >> 6, lane = tid & 63, lhi = lane >> 4, llo = lane & 15;
    stage_h(h2all + (size_t)t * NB * NH, smem, tid);
    __syncthreads();

    f32x4 acc[2][2];
#pragma unroll
    for (int nt = 0; nt < 2; ++nt) {
        int col = wave * 32 + nt * 16 + llo;
        float bb = bout[col];
#pragma unroll
        for (int r = 0; r < 4; ++r) { acc[0][nt][r] = bb; acc[1][nt][r] = bb; }
    }
#pragma unroll 8
    for (int kt = 0; kt < 32; ++kt) {
        int kk = kt * 32 + lhi * 8;
        f16x8 a0 = afrag(smem, llo, kk);
        f16x8 a1 = afrag(smem, 16 + llo, kk);
#pragma unroll
        for (int nt = 0; nt < 2; ++nt) {
            int col = wave * 32 + nt * 16 + llo;
            f16x8 bf = *(const f16x8*)(Wout + (size_t)col * NH + kk);
            acc[0][nt] = MFMA16(a0, bf, acc[0][nt]);
            acc[1][nt] = MFMA16(a1, bf, acc[1][nt]);
        }
    }
#pragma unroll
    for (int nt = 0; nt < 2; ++nt) {
        int col = wave * 32 + nt * 16 + llo;
#pragma unroll
        for (int r = 0; r < 4; ++r) {
            out[(size_t)(lhi * 4 + r) * NT * NO + (size_t)t * NO + col] = acc[0][nt][r];
            out[(size_t)(16 + lhi * 4 + r) * NT * NO + (size_t)t * NO + col] = acc[1][nt][r];
        }
    }
}

extern "C" void kernel_launch(void* const* d_in, const int* in_sizes, int n_in,
                              void* d_out, int out_size, void* d_ws, size_t ws_size,
                              hipStream_t stream)
{
    const float* state = (const float*)d_in[0];
    const float* Wih0f = (const float*)d_in[1];
    const float* Whh0f = (const float*)d_in[2];
    const float* b0    = (const float*)d_in[3];
    const float* Wih1f = (const float*)d_in[4];
    const float* Whh1f = (const float*)d_in[5];
    const float* b1    = (const float*)d_in[6];
    const float* Woutf = (const float*)d_in[7];
    const float* bout  = (const float*)d_in[8];
    float* out = (float*)d_out;
    (void)in_sizes; (void)n_in; (void)out_size; (void)ws_size;

    size_t off = 0;
    char* base = (char*)d_ws;
    auto alloc = [&](size_t bytes) -> void* {
        void* p = base + off;
        off += (bytes + 255) & ~(size_t)255;
        return p;
    };
    f16* state16 = (f16*)alloc((size_t)NB * NT * NI * 2);
    f16* Wout    = (f16*)alloc((size_t)NO * NH * 2);
    f16* h1all   = (f16*)alloc((size_t)NT * NB * NH * 2);
    f16* h2all   = (f16*)alloc((size_t)NT * NB * NH * 2);

    convf16<<<(NB * NT * NI + 255) / 256, 256, 0, stream>>>(state, state16, NB * NT * NI);
    convf16<<<(NO * NH + 255) / 256, 256, 0, stream>>>(Woutf, Wout, NO * NH);
    // sentinel-fill h1all+h2all (contiguous) — consumers bypass L2 (SC01)
    hipMemsetAsync(h1all, 0x7F, (size_t)2 * NT * NB * NH * 2, stream);

    hipFuncSetAttribute((const void*)persist,
                        hipFuncAttributeMaxDynamicSharedMemorySize, 86016);
    persist<<<256, 256, 86016, stream>>>(Wih0f, Whh0f, b0, Wih1f, Whh1f, b1,
                                         state16, h1all, h2all);
    head_kernel<<<NT, 256, 0, stream>>>(h2all, Wout, bout, out);
}